// Round 2
// baseline (25379.137 us; speedup 1.0000x reference)
//
#include <hip/hip_runtime.h>
#include <math.h>

#define NPIX 1600   // 40*40

__constant__ float c_aw[5] = {1.19f, 2.79f, 4.53f, 8.06f, 10.32f};
__constant__ float c_ah[5] = {1.98f, 4.59f, 8.92f, 5.29f, 10.65f};

// ---------------------------------------------------------------------------
// conv3x3 (SAME, stride 1) over 40x40, CIN -> 64*gridDim.z out channels.
// Block tile: 32 px (8 wide x 4 high) x 64 oc, 256 threads, thread tile 4px x 2oc.
// K staged in chunks of 8 input channels, LDS ping-pong double-buffered,
// register-staged global loads (issue-early / write-late), 1 barrier/chunk.
// Accumulation order per output: (chunk, ic, dy, dx) — identical to the
// round-1 kernel (bitwise-same outputs).
// ---------------------------------------------------------------------------
template<int CIN>
__global__ __launch_bounds__(256, 3)
void conv3x3_kernel(const float* __restrict__ in, const float* __restrict__ w,
                    const float* __restrict__ scale, const float* __restrict__ shift,
                    float* __restrict__ out)
{
    const int xt  = blockIdx.x;        // 0..4  (8-wide col tiles)
    const int yt  = blockIdx.y;        // 0..9  (4-high row tiles)
    const int ocb = blockIdx.z << 6;   // 16 oc blocks of 64
    const int tid = threadIdx.x;
    const int oc2 = tid & 31;          // 2 oc per thread
    const int ty  = tid >> 5;          // 0..7 px groups
    const int py  = ty >> 1;           // row 0..3 within tile
    const int pxo = (ty & 1) << 2;     // col 0 or 4

    __shared__ float wl[2][4608];      // [buf][(ic*9+tap)*64 + oc]
    __shared__ float patch[2][576];    // [buf][ic*72 + row*12 + col], 6 rows x 10 cols

    const int y0 = yt*4 - 1;           // patch origin (global, incl. halo)
    const int x0 = xt*8 - 1;

    float acc[4][2];
#pragma unroll
    for (int j = 0; j < 4; ++j) { acc[j][0] = 0.f; acc[j][1] = 0.f; }

    const bool isW = tid < 128;        // waves 0,1 stage weights; waves 2,3 stage patch
    const int wo = tid >> 1;           // oc within block (weight loader)
    const int wh = (tid & 1) * 36;     // half of the 72-float (8ic x 9tap) run
    const int pt = tid - 128;          // patch loader index

    float4 wreg[9];
    float  preg[4];

    auto LOAD = [&](int c0) {
        if (isW) {
            const float* wp = w + (size_t)(ocb + wo)*(CIN*9) + c0*9 + wh;
#pragma unroll
            for (int m = 0; m < 9; ++m) wreg[m] = ((const float4*)wp)[m];
        } else {
#pragma unroll
            for (int q = 0; q < 4; ++q) {
                const int e = pt + (q << 7);
                float v = 0.f;
                if (e < 480) {
                    const int ch  = e / 60;
                    const int rem = e - ch*60;
                    const int pr  = rem / 10;
                    const int pc  = rem - pr*10;
                    const int gy = y0 + pr, gx = x0 + pc;
                    if ((unsigned)gy < 40u && (unsigned)gx < 40u)
                        v = in[(size_t)(c0+ch)*NPIX + gy*40 + gx];
                }
                preg[q] = v;
            }
        }
    };
    auto WRITE = [&](int buf) {
        if (isW) {
#pragma unroll
            for (int m = 0; m < 9; ++m) {
                const int rr = wh + (m << 2);
                wl[buf][(rr+0)*64 + wo] = wreg[m].x;
                wl[buf][(rr+1)*64 + wo] = wreg[m].y;
                wl[buf][(rr+2)*64 + wo] = wreg[m].z;
                wl[buf][(rr+3)*64 + wo] = wreg[m].w;
            }
        } else {
#pragma unroll
            for (int q = 0; q < 4; ++q) {
                const int e = pt + (q << 7);
                if (e < 480) {
                    const int ch  = e / 60;
                    const int rem = e - ch*60;
                    const int pr  = rem / 10;
                    const int pc  = rem - pr*10;
                    patch[buf][ch*72 + pr*12 + pc] = preg[q];
                }
            }
        }
    };
    auto COMPUTE = [&](int buf) {
        const float* wb = &wl[buf][oc2 << 1];
        const float* pb = &patch[buf][py*12 + pxo];
#pragma unroll
        for (int i = 0; i < 8; ++i) {
#pragma unroll
            for (int dy = 0; dy < 3; ++dy) {
                float a[6];
#pragma unroll
                for (int q = 0; q < 6; ++q) a[q] = pb[i*72 + dy*12 + q];
#pragma unroll
                for (int dx = 0; dx < 3; ++dx) {
                    const float2 b = *(const float2*)&wb[(i*9 + dy*3 + dx)*64];
#pragma unroll
                    for (int j = 0; j < 4; ++j) {
                        acc[j][0] = fmaf(a[dx+j], b.x, acc[j][0]);
                        acc[j][1] = fmaf(a[dx+j], b.y, acc[j][1]);
                    }
                }
            }
        }
    };

    const int NC = CIN / 8;
    LOAD(0);
    WRITE(0);
    for (int c = 0; c < NC; ++c) {
        __syncthreads();
        if (c + 1 < NC) LOAD((c + 1) << 3);
        COMPUTE(c & 1);
        if (c + 1 < NC) WRITE((c + 1) & 1);
    }

    // epilogue: BN + leaky ReLU, float4 stores (4 px are consecutive cols of one row)
    const int gy = yt*4 + py;
    const int gx = xt*8 + pxo;
#pragma unroll
    for (int k = 0; k < 2; ++k) {
        const int oc = ocb + (oc2 << 1) + k;
        const float s = scale[oc], sh = shift[oc];
        float4 o4; float v;
        v = fmaf(acc[0][k], s, sh); o4.x = v > 0.f ? v : 0.1f*v;
        v = fmaf(acc[1][k], s, sh); o4.y = v > 0.f ? v : 0.1f*v;
        v = fmaf(acc[2][k], s, sh); o4.z = v > 0.f ? v : 0.1f*v;
        v = fmaf(acc[3][k], s, sh); o4.w = v > 0.f ? v : 0.1f*v;
        *(float4*)&out[(size_t)oc*NPIX + gy*40 + gx] = o4;
    }
}

// ---------------------------------------------------------------------------
// conv1x1 512->64 @80x80 + BN + lrelu + reorg(s=2), writes X channels 0..255
// ---------------------------------------------------------------------------
__global__ __launch_bounds__(256)
void conv1x1_reorg_kernel(const float* __restrict__ in, const float* __restrict__ w,
                          const float* __restrict__ scale, const float* __restrict__ shift,
                          float* __restrict__ X)
{
    const int px0 = blockIdx.x << 6;   // 100 blocks x 64 linear pixels (of 6400)
    const int tid = threadIdx.x;
    const int tx  = tid & 15;
    const int ty  = tid >> 4;

    __shared__ float il[8*64];
    __shared__ float wlr[8*64];

    float acc[4][4];
#pragma unroll
    for (int j = 0; j < 4; ++j)
#pragma unroll
        for (int k = 0; k < 4; ++k) acc[j][k] = 0.f;

    for (int c0 = 0; c0 < 512; c0 += 8) {
        __syncthreads();
        {
            int e = tid;
#pragma unroll
            for (int q = 0; q < 2; ++q, e += 256) {
                const int ch = e >> 6, p = e & 63;
                il[ch*64 + p] = in[(size_t)(c0+ch)*6400 + px0 + p];
            }
            e = tid;
#pragma unroll
            for (int q = 0; q < 2; ++q, e += 256) {
                const int o = e >> 3, cc = e & 7;
                wlr[cc*64 + o] = w[o*512 + c0 + cc];
            }
        }
        __syncthreads();
#pragma unroll
        for (int cc = 0; cc < 8; ++cc) {
            const float4 a4 = *(const float4*)&il[cc*64 + (ty<<2)];
            const float4 b4 = *(const float4*)&wlr[cc*64 + (tx<<2)];
            const float a[4] = {a4.x, a4.y, a4.z, a4.w};
            const float b[4] = {b4.x, b4.y, b4.z, b4.w};
#pragma unroll
            for (int j = 0; j < 4; ++j)
#pragma unroll
                for (int k = 0; k < 4; ++k)
                    acc[j][k] = fmaf(a[j], b[k], acc[j][k]);
        }
    }

#pragma unroll
    for (int j = 0; j < 4; ++j) {
        const int px = px0 + (ty<<2) + j;
        const int y2 = px / 80, x2 = px - y2*80;
        const int q  = (y2 & 1)*2 + (x2 & 1);
        const int yo = y2 >> 1, xo = x2 >> 1;
#pragma unroll
        for (int k = 0; k < 4; ++k) {
            const int oc = (tx<<2) + k;
            float v = fmaf(acc[j][k], scale[oc], shift[oc]);
            v = v > 0.f ? v : 0.1f*v;
            X[(size_t)(q*64 + oc)*NPIX + yo*40 + xo] = v;
        }
    }
}

// ---------------------------------------------------------------------------
// conv1x1 1024->125 @40x40 (no bias here; readers add bp)
// ---------------------------------------------------------------------------
__global__ __launch_bounds__(256)
void conv1x1_pred_kernel(const float* __restrict__ in, const float* __restrict__ w,
                         float* __restrict__ pred)
{
    const int px0 = blockIdx.x << 5;   // 50 blocks x 32 px
    const int tid = threadIdx.x;
    const int tx  = tid & 15;
    const int ty  = tid >> 4;

    __shared__ float il[8*32];
    __shared__ float wlp[8*128];

    float acc[2][8];
#pragma unroll
    for (int j = 0; j < 2; ++j)
#pragma unroll
        for (int k = 0; k < 8; ++k) acc[j][k] = 0.f;

    for (int c0 = 0; c0 < 1024; c0 += 8) {
        __syncthreads();
        {
            const int ch = tid >> 5, p = tid & 31;
            il[ch*32 + p] = in[(size_t)(c0+ch)*NPIX + px0 + p];
        }
#pragma unroll
        for (int q = 0; q < 4; ++q) {
            const int e = tid + q*256;
            const int o = e >> 3, cc = e & 7;
            wlp[cc*128 + o] = (o < 125) ? w[o*1024 + c0 + cc] : 0.f;
        }
        __syncthreads();
#pragma unroll
        for (int cc = 0; cc < 8; ++cc) {
            const float a0 = il[cc*32 + (ty<<1)];
            const float a1 = il[cc*32 + (ty<<1) + 1];
            const float4 b0 = *(const float4*)&wlp[cc*128 + (tx<<3)];
            const float4 b1 = *(const float4*)&wlp[cc*128 + (tx<<3) + 4];
            const float b[8] = {b0.x,b0.y,b0.z,b0.w,b1.x,b1.y,b1.z,b1.w};
#pragma unroll
            for (int k = 0; k < 8; ++k) {
                acc[0][k] = fmaf(a0, b[k], acc[0][k]);
                acc[1][k] = fmaf(a1, b[k], acc[1][k]);
            }
        }
    }
#pragma unroll
    for (int k = 0; k < 8; ++k) {
        const int oc = (tx<<3) + k;
        if (oc < 125) {
#pragma unroll
            for (int j = 0; j < 2; ++j)
                pred[(size_t)oc*NPIX + px0 + (ty<<1) + j] = acc[j][k];
        }
    }
}

// ---------------------------------------------------------------------------
// scores = sigmoid(conf) * softmax(cls) for 8000 (px,anchor) pairs
// ---------------------------------------------------------------------------
__global__ __launch_bounds__(256)
void score_kernel(const float* __restrict__ pred, const float* __restrict__ bp,
                  float* __restrict__ scores)
{
    const int id = blockIdx.x*256 + threadIdx.x;
    if (id >= 8000) return;
    const int a  = id / 1600;
    const int px = id - a*1600;
    const float conf = pred[a*NPIX + px] + bp[a];
    float cls[20];
    float m = -INFINITY;
#pragma unroll
    for (int c = 0; c < 20; ++c) {
        cls[c] = pred[(5 + a*20 + c)*NPIX + px] + bp[5 + a*20 + c];
        m = fmaxf(m, cls[c]);
    }
    float ssum = 0.f;
#pragma unroll
    for (int c = 0; c < 20; ++c) { cls[c] = expf(cls[c] - m); ssum += cls[c]; }
    const float sig = 1.f / (1.f + expf(-conf));
    const float f = sig / ssum;
    const int base = (px*5 + a)*20;
#pragma unroll
    for (int c = 0; c < 20; ++c) scores[base + c] = cls[c] * f;
}

// ---------------------------------------------------------------------------
// exact top-100 via 3-level radix select on positive-float bits (12/12/8)
// ---------------------------------------------------------------------------
__global__ __launch_bounds__(256)
void hist1_kernel(const float* __restrict__ scores, unsigned* __restrict__ hist)
{
    __shared__ unsigned h[4096];
    for (int i = threadIdx.x; i < 4096; i += 256) h[i] = 0u;
    __syncthreads();
    for (int id = blockIdx.x*256 + threadIdx.x; id < 160000; id += 80*256)
        atomicAdd(&h[__float_as_uint(scores[id]) >> 20], 1u);
    __syncthreads();
    for (int i = threadIdx.x; i < 4096; i += 256)
        if (h[i]) atomicAdd(&hist[i], h[i]);
}

__global__ __launch_bounds__(256)
void hist2_kernel(const float* __restrict__ scores, const unsigned* __restrict__ meta,
                  unsigned* __restrict__ hist)
{
    const int id = blockIdx.x*256 + threadIdx.x;
    if (id >= 160000) return;
    const unsigned u = __float_as_uint(scores[id]);
    if ((u >> 20) == meta[0]) atomicAdd(&hist[(u >> 8) & 0xFFFu], 1u);
}

__global__ __launch_bounds__(256)
void hist3_kernel(const float* __restrict__ scores, const unsigned* __restrict__ meta,
                  unsigned* __restrict__ hist)
{
    const int id = blockIdx.x*256 + threadIdx.x;
    if (id >= 160000) return;
    const unsigned u = __float_as_uint(scores[id]);
    const unsigned key = (meta[0] << 12) | meta[2];
    if ((u >> 8) == key) atomicAdd(&hist[u & 0xFFu], 1u);
}

__global__ __launch_bounds__(256)
void scan_kernel(const unsigned* __restrict__ hist, int nbins,
                 unsigned* __restrict__ meta, int mode)
{
    __shared__ unsigned seg[256];
    const int tid = threadIdx.x;
    const int spb = nbins >> 8;    // bins per segment (16 or 1)
    unsigned s = 0;
    for (int k = 0; k < spb; ++k) s += hist[tid*spb + k];
    seg[tid] = s;
    __syncthreads();
    if (tid == 0) {
        unsigned need = 100u;
        if (mode == 2) need = 100u - meta[1];
        else if (mode == 3) need = 100u - meta[3];
        unsigned cum = 0;
        int sgi = 255;
        while (sgi > 0 && cum + seg[sgi] < need) { cum += seg[sgi]; --sgi; }
        int b = sgi*spb + spb - 1;
        while (b > sgi*spb && cum + hist[b] < need) { cum += hist[b]; --b; }
        if (mode == 1)      { meta[0] = (unsigned)b; meta[1] = cum; }
        else if (mode == 2) { meta[2] = (unsigned)b; meta[3] = meta[1] + cum; }
        else {
            meta[4] = (meta[0] << 20) | (meta[2] << 8) | (unsigned)b;  // exact bits of 100th value
            meta[5] = meta[3] + cum;                                    // n strictly greater
        }
    }
}

__global__ __launch_bounds__(256)
void collect_kernel(const float* __restrict__ scores, unsigned* __restrict__ meta,
                    float* __restrict__ gt_val, unsigned* __restrict__ gt_idx,
                    unsigned* __restrict__ eq_idx)
{
    const int id = blockIdx.x*256 + threadIdx.x;
    if (id >= 160000) return;
    const float v = scores[id];
    const unsigned u = __float_as_uint(v);
    const unsigned T = meta[4];
    if (u > T) {
        const unsigned p = atomicAdd(&meta[8], 1u);
        if (p < 128u) { gt_val[p] = v; gt_idx[p] = (unsigned)id; }
    } else if (u == T) {
        const unsigned p = atomicAdd(&meta[9], 1u);
        if (p < 1024u) eq_idx[p] = (unsigned)id;
    }
}

// ---------------------------------------------------------------------------
// final: assemble top-100 (stable ties), bitonic sort desc, decode, NMS, write
// ---------------------------------------------------------------------------
__global__ __launch_bounds__(128)
void final_kernel(const float* __restrict__ pred, const float* __restrict__ bp,
                  const unsigned* __restrict__ meta,
                  const float* __restrict__ gt_val, const unsigned* __restrict__ gt_idx,
                  const unsigned* __restrict__ eq_idx,
                  float* __restrict__ out)
{
    __shared__ float    sval[128];
    __shared__ unsigned sidx[128];
    __shared__ float bx1[100], by1[100], bx2[100], by2[100], sarea[100], sscore[100];
    __shared__ int   slab[100];
    __shared__ int   skeep[100];

    const int tid = threadIdx.x;
    const unsigned T    = meta[4];
    const unsigned n_gt = meta[5];
    const unsigned n_eq = meta[9] < 1024u ? meta[9] : 1024u;
    const int n_take = 100 - (int)n_gt;

    sval[tid] = -1.f;
    sidx[tid] = 0xFFFFFFFFu;
    if (tid < (int)n_gt) { sval[tid] = gt_val[tid]; sidx[tid] = gt_idx[tid]; }
    __syncthreads();
    if (tid == 0) {
        // values equal to threshold: stable top_k takes smallest indices first
        unsigned lastp1 = 0;
        const float tv = __uint_as_float(T);
        for (int t = 0; t < n_take; ++t) {
            unsigned best = 0xFFFFFFFFu;
            for (unsigned e = 0; e < n_eq; ++e) {
                const unsigned v = eq_idx[e];
                if (v >= lastp1 && v < best) best = v;
            }
            sval[n_gt + t] = tv;
            sidx[n_gt + t] = best;
            lastp1 = best + 1;
        }
    }
    __syncthreads();

    // bitonic sort of 128 (desc value, ties asc index); padding (-1) sinks
    for (int k = 2; k <= 128; k <<= 1) {
        for (int j = k >> 1; j > 0; j >>= 1) {
            const int ixj = tid ^ j;
            if (ixj > tid) {
                const float v0 = sval[tid], v1 = sval[ixj];
                const unsigned i0 = sidx[tid], i1 = sidx[ixj];
                const bool prec = (v0 > v1) || (v0 == v1 && i0 < i1);
                const bool asc  = ((tid & k) == 0);
                if (asc ? !prec : prec) {
                    sval[tid] = v1; sval[ixj] = v0;
                    sidx[tid] = i1; sidx[ixj] = i0;
                }
            }
            __syncthreads();
        }
    }

    if (tid < 100) {
        const float sc = sval[tid];
        const unsigned idx = sidx[tid];
        const int ai   = (int)(idx / 20u);
        const int lab  = (int)(idx - (unsigned)ai*20u);
        const int cell = ai / 5;
        const int a    = ai - cell*5;
        const int gx = cell % 40, gy = cell / 40;
        const int rb = 105 + a*4;
        const float t0 = pred[(rb+0)*NPIX + cell] + bp[rb+0];
        const float t1 = pred[(rb+1)*NPIX + cell] + bp[rb+1];
        const float t2 = pred[(rb+2)*NPIX + cell] + bp[rb+2];
        const float t3 = pred[(rb+3)*NPIX + cell] + bp[rb+3];
        const float cx = (1.f/(1.f+expf(-t0)) + (float)gx) * 32.f;
        const float cy = (1.f/(1.f+expf(-t1)) + (float)gy) * 32.f;
        const float bw = expf(t2) * c_aw[a] * 32.f;
        const float bh = expf(t3) * c_ah[a] * 32.f;
        bx1[tid] = cx - 0.5f*bw;
        by1[tid] = cy - 0.5f*bh;
        bx2[tid] = cx + 0.5f*bw;
        by2[tid] = cy + 0.5f*bh;
        sarea[tid]  = (bx2[tid]-bx1[tid]) * (by2[tid]-by1[tid]);
        slab[tid]   = lab;
        sscore[tid] = sc;
        skeep[tid]  = (sc > 0.001f) ? 1 : 0;
    }
    __syncthreads();

    // greedy class-aware NMS (reference semantics)
    for (int i = 0; i < 99; ++i) {
        if (tid < 100 && tid > i) {
            if (skeep[i] && skeep[tid] && slab[tid] == slab[i]) {
                const float xx1 = fmaxf(bx1[i], bx1[tid]);
                const float yy1 = fmaxf(by1[i], by1[tid]);
                const float xx2 = fminf(bx2[i], bx2[tid]);
                const float yy2 = fminf(by2[i], by2[tid]);
                const float inter = fmaxf(1e-10f, xx2-xx1) * fmaxf(1e-10f, yy2-yy1);
                const float iou = inter / (sarea[i] + sarea[tid] - inter);
                if (iou > 0.6f) skeep[tid] = 0;
            }
        }
        __syncthreads();
    }

    if (tid < 100) {
        const bool kp = skeep[tid] != 0;
        const float q[4] = {bx1[tid], by1[tid], bx2[tid], by2[tid]};
#pragma unroll
        for (int k = 0; k < 4; ++k) {
            float v = q[k] / 1280.f;
            v = fminf(fmaxf(v, 0.f), 1.f);
            out[tid*4 + k] = kp ? v : 0.f;
        }
        out[400 + tid] = kp ? sscore[tid] : 0.f;
        out[500 + tid] = kp ? (float)slab[tid] : -1.f;
        out[600 + tid] = kp ? 1.f : 0.f;
    }
}

// ---------------------------------------------------------------------------
extern "C" void kernel_launch(void* const* d_in, const int* in_sizes, int n_in,
                              void* d_out, int out_size, void* d_ws, size_t ws_size,
                              hipStream_t stream)
{
    const float* c4  = (const float*)d_in[0];
    const float* c5  = (const float*)d_in[1];
    const float* w1a = (const float*)d_in[2];
    const float* s1a = (const float*)d_in[3];
    const float* b1a = (const float*)d_in[4];
    const float* w1b = (const float*)d_in[5];
    const float* s1b = (const float*)d_in[6];
    const float* b1b = (const float*)d_in[7];
    const float* wr  = (const float*)d_in[8];
    const float* sr  = (const float*)d_in[9];
    const float* br  = (const float*)d_in[10];
    const float* w2  = (const float*)d_in[11];
    const float* s2  = (const float*)d_in[12];
    const float* b2  = (const float*)d_in[13];
    const float* wp  = (const float*)d_in[14];
    const float* bp  = (const float*)d_in[15];

    float* ws   = (float*)d_ws;
    float* p5a  = ws;                         // 1024*1600
    float* X    = p5a + 1024*NPIX;            // 1280*1600 (concat buffer)
    float* p5c  = X + 1280*NPIX;              // 1024*1600
    float* pred = p5c + 1024*NPIX;            // 125*1600
    float* scores = pred + 125*NPIX;          // 160000
    unsigned* hist1 = (unsigned*)(scores + 160000);  // 4096
    unsigned* hist2 = hist1 + 4096;                  // 4096
    unsigned* hist3 = hist2 + 4096;                  // 256
    unsigned* meta  = hist3 + 256;                   // 16
    float*    gt_val = (float*)(meta + 16);          // 128
    unsigned* gt_idx = (unsigned*)(gt_val + 128);    // 128
    unsigned* eq_idx = gt_idx + 128;                 // 1024

    hipMemsetAsync(hist1, 0, (4096 + 4096 + 256 + 16) * sizeof(unsigned), stream);

    const dim3 g3(5, 10, 16);
    conv3x3_kernel<1024><<<g3, 256, 0, stream>>>(c5,  w1a, s1a, b1a, p5a);
    conv3x3_kernel<1024><<<g3, 256, 0, stream>>>(p5a, w1b, s1b, b1b, X + 256*NPIX);
    conv1x1_reorg_kernel<<<100, 256, 0, stream>>>(c4, wr, sr, br, X);
    conv3x3_kernel<1280><<<g3, 256, 0, stream>>>(X, w2, s2, b2, p5c);
    conv1x1_pred_kernel<<<50, 256, 0, stream>>>(p5c, wp, pred);

    score_kernel<<<32, 256, 0, stream>>>(pred, bp, scores);
    hist1_kernel<<<80, 256, 0, stream>>>(scores, hist1);
    scan_kernel<<<1, 256, 0, stream>>>(hist1, 4096, meta, 1);
    hist2_kernel<<<625, 256, 0, stream>>>(scores, meta, hist2);
    scan_kernel<<<1, 256, 0, stream>>>(hist2, 4096, meta, 2);
    hist3_kernel<<<625, 256, 0, stream>>>(scores, meta, hist3);
    scan_kernel<<<1, 256, 0, stream>>>(hist3, 256, meta, 3);
    collect_kernel<<<625, 256, 0, stream>>>(scores, meta, gt_val, gt_idx, eq_idx);
    final_kernel<<<1, 128, 0, stream>>>(pred, bp, meta, gt_val, gt_idx, eq_idx, (float*)d_out);
}

// Round 3
// 2775.365 us; speedup vs baseline: 9.1444x; 9.1444x over previous
//
#include <hip/hip_runtime.h>
#include <math.h>

#define NPIX 1600   // 40*40

__constant__ float c_aw[5] = {1.19f, 2.79f, 4.53f, 8.06f, 10.32f};
__constant__ float c_ah[5] = {1.98f, 4.59f, 8.92f, 5.29f, 10.65f};

// ---------------------------------------------------------------------------
// conv3x3 (SAME, stride 1) over 40x40, CIN -> 32*gridDim.z out channels.
// Block tile: 64 px (8x8 spatial) x 32 oc. Thread tile: 4 px x 2 oc.
// K staged in chunks of 8 input channels, DIRECT global->LDS staging
// (round-1 structure: 48 VGPR, no register-held tiles, 2 barriers/chunk).
// Grid (5,5,32) = 800 blocks for ~3 blocks/CU occupancy.
// Per-output accumulation order (chunk, ic, dy, dx) identical to round 1
// => bitwise-identical conv outputs.
// ---------------------------------------------------------------------------
template<int CIN>
__global__ __launch_bounds__(256)
void conv3x3_kernel(const float* __restrict__ in, const float* __restrict__ w,
                    const float* __restrict__ scale, const float* __restrict__ shift,
                    float* __restrict__ out)
{
    const int ox  = blockIdx.x, oy = blockIdx.y;
    const int ocb = blockIdx.z << 5;  // 32 oc per block
    const int tid = threadIdx.x;
    const int tx  = tid & 15;         // oc group: oc = ocb + tx*2 + k
    const int ty  = tid >> 4;         // px group: row r = ty>>1, xoff = (ty&1)*4
    const int r    = ty >> 1;
    const int xoff = (ty & 1) << 2;

    __shared__ float wl[8*9*32];      // [(ic*9+tap)*32 + oc]  (9.2 KB)
    __shared__ float patch[8*10*12];  // [ic][py][px] stride 12 (3.8 KB)

    float acc[4][2];
#pragma unroll
    for (int j = 0; j < 4; ++j) { acc[j][0] = 0.f; acc[j][1] = 0.f; }

    const int y0 = oy*8 - 1;
    const int x0 = ox*8 - 1;

    for (int c0 = 0; c0 < CIN; c0 += 8) {
        __syncthreads();
        if (tid < 64) {
            // weights: 32 oc x 8 ic x 9 taps = 2304 floats. 2 threads per oc,
            // each reads 36 contiguous floats (9x float4, 16B aligned).
            const int o  = tid >> 1;
            const int rh = (tid & 1) * 36;
            const float* wp = w + (size_t)(ocb + o)*(CIN*9) + c0*9 + rh;
#pragma unroll
            for (int m = 0; m < 9; ++m) {
                const float4 v = ((const float4*)wp)[m];
                const int rr = rh + m*4;   // rr = ic*9 + tap
                wl[(rr+0)*32 + o] = v.x;
                wl[(rr+1)*32 + o] = v.y;
                wl[(rr+2)*32 + o] = v.z;
                wl[(rr+3)*32 + o] = v.w;
            }
        } else {
            // input patch 8ch x 10x10 (zero-padded borders), 192 threads
            const int t = tid - 64;
            for (int e = t; e < 800; e += 192) {
                const int ch  = e / 100;
                const int rem = e - ch*100;
                const int py  = rem / 10;
                const int pxx = rem - py*10;
                const int gy = y0 + py, gx = x0 + pxx;
                float v = 0.f;
                if ((unsigned)gy < 40u && (unsigned)gx < 40u)
                    v = in[(size_t)(c0+ch)*NPIX + gy*40 + gx];
                patch[ch*120 + py*12 + pxx] = v;
            }
        }
        __syncthreads();
#pragma unroll
        for (int i = 0; i < 8; ++i) {
#pragma unroll
            for (int dy = 0; dy < 3; ++dy) {
                const float* prow = &patch[i*120 + (r+dy)*12 + xoff];
                float a[6];
#pragma unroll
                for (int q = 0; q < 6; ++q) a[q] = prow[q];
#pragma unroll
                for (int dx = 0; dx < 3; ++dx) {
                    const float2 b = *(const float2*)&wl[(i*9 + dy*3 + dx)*32 + (tx<<1)];
#pragma unroll
                    for (int j = 0; j < 4; ++j) {
                        const float av = a[dx + j];
                        acc[j][0] = fmaf(av, b.x, acc[j][0]);
                        acc[j][1] = fmaf(av, b.y, acc[j][1]);
                    }
                }
            }
        }
    }

    // epilogue: BN + leaky ReLU, coalesced float4 stores
    const int gy = oy*8 + r;
    const int gx = ox*8 + xoff;
#pragma unroll
    for (int k = 0; k < 2; ++k) {
        const int oc = ocb + (tx<<1) + k;
        const float s = scale[oc], sh = shift[oc];
        float4 o4; float v;
        v = fmaf(acc[0][k], s, sh); o4.x = v > 0.f ? v : 0.1f*v;
        v = fmaf(acc[1][k], s, sh); o4.y = v > 0.f ? v : 0.1f*v;
        v = fmaf(acc[2][k], s, sh); o4.z = v > 0.f ? v : 0.1f*v;
        v = fmaf(acc[3][k], s, sh); o4.w = v > 0.f ? v : 0.1f*v;
        *(float4*)&out[(size_t)oc*NPIX + gy*40 + gx] = o4;
    }
}

// ---------------------------------------------------------------------------
// conv1x1 512->64 @80x80 + BN + lrelu + reorg(s=2), writes X channels 0..255
// ---------------------------------------------------------------------------
__global__ __launch_bounds__(256)
void conv1x1_reorg_kernel(const float* __restrict__ in, const float* __restrict__ w,
                          const float* __restrict__ scale, const float* __restrict__ shift,
                          float* __restrict__ X)
{
    const int px0 = blockIdx.x << 6;   // 100 blocks x 64 linear pixels (of 6400)
    const int tid = threadIdx.x;
    const int tx  = tid & 15;
    const int ty  = tid >> 4;

    __shared__ float il[8*64];
    __shared__ float wlr[8*64];

    float acc[4][4];
#pragma unroll
    for (int j = 0; j < 4; ++j)
#pragma unroll
        for (int k = 0; k < 4; ++k) acc[j][k] = 0.f;

    for (int c0 = 0; c0 < 512; c0 += 8) {
        __syncthreads();
        {
            int e = tid;
#pragma unroll
            for (int q = 0; q < 2; ++q, e += 256) {
                const int ch = e >> 6, p = e & 63;
                il[ch*64 + p] = in[(size_t)(c0+ch)*6400 + px0 + p];
            }
            e = tid;
#pragma unroll
            for (int q = 0; q < 2; ++q, e += 256) {
                const int o = e >> 3, cc = e & 7;
                wlr[cc*64 + o] = w[o*512 + c0 + cc];
            }
        }
        __syncthreads();
#pragma unroll
        for (int cc = 0; cc < 8; ++cc) {
            const float4 a4 = *(const float4*)&il[cc*64 + (ty<<2)];
            const float4 b4 = *(const float4*)&wlr[cc*64 + (tx<<2)];
            const float a[4] = {a4.x, a4.y, a4.z, a4.w};
            const float b[4] = {b4.x, b4.y, b4.z, b4.w};
#pragma unroll
            for (int j = 0; j < 4; ++j)
#pragma unroll
                for (int k = 0; k < 4; ++k)
                    acc[j][k] = fmaf(a[j], b[k], acc[j][k]);
        }
    }

#pragma unroll
    for (int j = 0; j < 4; ++j) {
        const int px = px0 + (ty<<2) + j;
        const int y2 = px / 80, x2 = px - y2*80;
        const int q  = (y2 & 1)*2 + (x2 & 1);
        const int yo = y2 >> 1, xo = x2 >> 1;
#pragma unroll
        for (int k = 0; k < 4; ++k) {
            const int oc = (tx<<2) + k;
            float v = fmaf(acc[j][k], scale[oc], shift[oc]);
            v = v > 0.f ? v : 0.1f*v;
            X[(size_t)(q*64 + oc)*NPIX + yo*40 + xo] = v;
        }
    }
}

// ---------------------------------------------------------------------------
// conv1x1 1024->125 @40x40 (no bias here; readers add bp)
// ---------------------------------------------------------------------------
__global__ __launch_bounds__(256)
void conv1x1_pred_kernel(const float* __restrict__ in, const float* __restrict__ w,
                         float* __restrict__ pred)
{
    const int px0 = blockIdx.x << 5;   // 50 blocks x 32 px
    const int tid = threadIdx.x;
    const int tx  = tid & 15;
    const int ty  = tid >> 4;

    __shared__ float il[8*32];
    __shared__ float wlp[8*128];

    float acc[2][8];
#pragma unroll
    for (int j = 0; j < 2; ++j)
#pragma unroll
        for (int k = 0; k < 8; ++k) acc[j][k] = 0.f;

    for (int c0 = 0; c0 < 1024; c0 += 8) {
        __syncthreads();
        {
            const int ch = tid >> 5, p = tid & 31;
            il[ch*32 + p] = in[(size_t)(c0+ch)*NPIX + px0 + p];
        }
#pragma unroll
        for (int q = 0; q < 4; ++q) {
            const int e = tid + q*256;
            const int o = e >> 3, cc = e & 7;
            wlp[cc*128 + o] = (o < 125) ? w[o*1024 + c0 + cc] : 0.f;
        }
        __syncthreads();
#pragma unroll
        for (int cc = 0; cc < 8; ++cc) {
            const float a0 = il[cc*32 + (ty<<1)];
            const float a1 = il[cc*32 + (ty<<1) + 1];
            const float4 b0 = *(const float4*)&wlp[cc*128 + (tx<<3)];
            const float4 b1 = *(const float4*)&wlp[cc*128 + (tx<<3) + 4];
            const float b[8] = {b0.x,b0.y,b0.z,b0.w,b1.x,b1.y,b1.z,b1.w};
#pragma unroll
            for (int k = 0; k < 8; ++k) {
                acc[0][k] = fmaf(a0, b[k], acc[0][k]);
                acc[1][k] = fmaf(a1, b[k], acc[1][k]);
            }
        }
    }
#pragma unroll
    for (int k = 0; k < 8; ++k) {
        const int oc = (tx<<3) + k;
        if (oc < 125) {
#pragma unroll
            for (int j = 0; j < 2; ++j)
                pred[(size_t)oc*NPIX + px0 + (ty<<1) + j] = acc[j][k];
        }
    }
}

// ---------------------------------------------------------------------------
// scores = sigmoid(conf) * softmax(cls) for 8000 (px,anchor) pairs
// ---------------------------------------------------------------------------
__global__ __launch_bounds__(256)
void score_kernel(const float* __restrict__ pred, const float* __restrict__ bp,
                  float* __restrict__ scores)
{
    const int id = blockIdx.x*256 + threadIdx.x;
    if (id >= 8000) return;
    const int a  = id / 1600;
    const int px = id - a*1600;
    const float conf = pred[a*NPIX + px] + bp[a];
    float cls[20];
    float m = -INFINITY;
#pragma unroll
    for (int c = 0; c < 20; ++c) {
        cls[c] = pred[(5 + a*20 + c)*NPIX + px] + bp[5 + a*20 + c];
        m = fmaxf(m, cls[c]);
    }
    float ssum = 0.f;
#pragma unroll
    for (int c = 0; c < 20; ++c) { cls[c] = expf(cls[c] - m); ssum += cls[c]; }
    const float sig = 1.f / (1.f + expf(-conf));
    const float f = sig / ssum;
    const int base = (px*5 + a)*20;
#pragma unroll
    for (int c = 0; c < 20; ++c) scores[base + c] = cls[c] * f;
}

// ---------------------------------------------------------------------------
// exact top-100 via 3-level radix select on positive-float bits (12/12/8)
// ---------------------------------------------------------------------------
__global__ __launch_bounds__(256)
void hist1_kernel(const float* __restrict__ scores, unsigned* __restrict__ hist)
{
    __shared__ unsigned h[4096];
    for (int i = threadIdx.x; i < 4096; i += 256) h[i] = 0u;
    __syncthreads();
    for (int id = blockIdx.x*256 + threadIdx.x; id < 160000; id += 80*256)
        atomicAdd(&h[__float_as_uint(scores[id]) >> 20], 1u);
    __syncthreads();
    for (int i = threadIdx.x; i < 4096; i += 256)
        if (h[i]) atomicAdd(&hist[i], h[i]);
}

__global__ __launch_bounds__(256)
void hist2_kernel(const float* __restrict__ scores, const unsigned* __restrict__ meta,
                  unsigned* __restrict__ hist)
{
    const int id = blockIdx.x*256 + threadIdx.x;
    if (id >= 160000) return;
    const unsigned u = __float_as_uint(scores[id]);
    if ((u >> 20) == meta[0]) atomicAdd(&hist[(u >> 8) & 0xFFFu], 1u);
}

__global__ __launch_bounds__(256)
void hist3_kernel(const float* __restrict__ scores, const unsigned* __restrict__ meta,
                  unsigned* __restrict__ hist)
{
    const int id = blockIdx.x*256 + threadIdx.x;
    if (id >= 160000) return;
    const unsigned u = __float_as_uint(scores[id]);
    const unsigned key = (meta[0] << 12) | meta[2];
    if ((u >> 8) == key) atomicAdd(&hist[u & 0xFFu], 1u);
}

__global__ __launch_bounds__(256)
void scan_kernel(const unsigned* __restrict__ hist, int nbins,
                 unsigned* __restrict__ meta, int mode)
{
    __shared__ unsigned seg[256];
    const int tid = threadIdx.x;
    const int spb = nbins >> 8;    // bins per segment (16 or 1)
    unsigned s = 0;
    for (int k = 0; k < spb; ++k) s += hist[tid*spb + k];
    seg[tid] = s;
    __syncthreads();
    if (tid == 0) {
        unsigned need = 100u;
        if (mode == 2) need = 100u - meta[1];
        else if (mode == 3) need = 100u - meta[3];
        unsigned cum = 0;
        int sgi = 255;
        while (sgi > 0 && cum + seg[sgi] < need) { cum += seg[sgi]; --sgi; }
        int b = sgi*spb + spb - 1;
        while (b > sgi*spb && cum + hist[b] < need) { cum += hist[b]; --b; }
        if (mode == 1)      { meta[0] = (unsigned)b; meta[1] = cum; }
        else if (mode == 2) { meta[2] = (unsigned)b; meta[3] = meta[1] + cum; }
        else {
            meta[4] = (meta[0] << 20) | (meta[2] << 8) | (unsigned)b;  // exact bits of 100th value
            meta[5] = meta[3] + cum;                                    // n strictly greater
        }
    }
}

__global__ __launch_bounds__(256)
void collect_kernel(const float* __restrict__ scores, unsigned* __restrict__ meta,
                    float* __restrict__ gt_val, unsigned* __restrict__ gt_idx,
                    unsigned* __restrict__ eq_idx)
{
    const int id = blockIdx.x*256 + threadIdx.x;
    if (id >= 160000) return;
    const float v = scores[id];
    const unsigned u = __float_as_uint(v);
    const unsigned T = meta[4];
    if (u > T) {
        const unsigned p = atomicAdd(&meta[8], 1u);
        if (p < 128u) { gt_val[p] = v; gt_idx[p] = (unsigned)id; }
    } else if (u == T) {
        const unsigned p = atomicAdd(&meta[9], 1u);
        if (p < 1024u) eq_idx[p] = (unsigned)id;
    }
}

// ---------------------------------------------------------------------------
// final: assemble top-100 (stable ties), bitonic sort desc, decode, NMS, write
// ---------------------------------------------------------------------------
__global__ __launch_bounds__(128)
void final_kernel(const float* __restrict__ pred, const float* __restrict__ bp,
                  const unsigned* __restrict__ meta,
                  const float* __restrict__ gt_val, const unsigned* __restrict__ gt_idx,
                  const unsigned* __restrict__ eq_idx,
                  float* __restrict__ out)
{
    __shared__ float    sval[128];
    __shared__ unsigned sidx[128];
    __shared__ float bx1[100], by1[100], bx2[100], by2[100], sarea[100], sscore[100];
    __shared__ int   slab[100];
    __shared__ int   skeep[100];

    const int tid = threadIdx.x;
    const unsigned T    = meta[4];
    const unsigned n_gt = meta[5];
    const unsigned n_eq = meta[9] < 1024u ? meta[9] : 1024u;
    const int n_take = 100 - (int)n_gt;

    sval[tid] = -1.f;
    sidx[tid] = 0xFFFFFFFFu;
    if (tid < (int)n_gt) { sval[tid] = gt_val[tid]; sidx[tid] = gt_idx[tid]; }
    __syncthreads();
    if (tid == 0) {
        // values equal to threshold: stable top_k takes smallest indices first
        unsigned lastp1 = 0;
        const float tv = __uint_as_float(T);
        for (int t = 0; t < n_take; ++t) {
            unsigned best = 0xFFFFFFFFu;
            for (unsigned e = 0; e < n_eq; ++e) {
                const unsigned v = eq_idx[e];
                if (v >= lastp1 && v < best) best = v;
            }
            sval[n_gt + t] = tv;
            sidx[n_gt + t] = best;
            lastp1 = best + 1;
        }
    }
    __syncthreads();

    // bitonic sort of 128 (desc value, ties asc index); padding (-1) sinks
    for (int k = 2; k <= 128; k <<= 1) {
        for (int j = k >> 1; j > 0; j >>= 1) {
            const int ixj = tid ^ j;
            if (ixj > tid) {
                const float v0 = sval[tid], v1 = sval[ixj];
                const unsigned i0 = sidx[tid], i1 = sidx[ixj];
                const bool prec = (v0 > v1) || (v0 == v1 && i0 < i1);
                const bool asc  = ((tid & k) == 0);
                if (asc ? !prec : prec) {
                    sval[tid] = v1; sval[ixj] = v0;
                    sidx[tid] = i1; sidx[ixj] = i0;
                }
            }
            __syncthreads();
        }
    }

    if (tid < 100) {
        const float sc = sval[tid];
        const unsigned idx = sidx[tid];
        const int ai   = (int)(idx / 20u);
        const int lab  = (int)(idx - (unsigned)ai*20u);
        const int cell = ai / 5;
        const int a    = ai - cell*5;
        const int gx = cell % 40, gy = cell / 40;
        const int rb = 105 + a*4;
        const float t0 = pred[(rb+0)*NPIX + cell] + bp[rb+0];
        const float t1 = pred[(rb+1)*NPIX + cell] + bp[rb+1];
        const float t2 = pred[(rb+2)*NPIX + cell] + bp[rb+2];
        const float t3 = pred[(rb+3)*NPIX + cell] + bp[rb+3];
        const float cx = (1.f/(1.f+expf(-t0)) + (float)gx) * 32.f;
        const float cy = (1.f/(1.f+expf(-t1)) + (float)gy) * 32.f;
        const float bw = expf(t2) * c_aw[a] * 32.f;
        const float bh = expf(t3) * c_ah[a] * 32.f;
        bx1[tid] = cx - 0.5f*bw;
        by1[tid] = cy - 0.5f*bh;
        bx2[tid] = cx + 0.5f*bw;
        by2[tid] = cy + 0.5f*bh;
        sarea[tid]  = (bx2[tid]-bx1[tid]) * (by2[tid]-by1[tid]);
        slab[tid]   = lab;
        sscore[tid] = sc;
        skeep[tid]  = (sc > 0.001f) ? 1 : 0;
    }
    __syncthreads();

    // greedy class-aware NMS (reference semantics)
    for (int i = 0; i < 99; ++i) {
        if (tid < 100 && tid > i) {
            if (skeep[i] && skeep[tid] && slab[tid] == slab[i]) {
                const float xx1 = fmaxf(bx1[i], bx1[tid]);
                const float yy1 = fmaxf(by1[i], by1[tid]);
                const float xx2 = fminf(bx2[i], bx2[tid]);
                const float yy2 = fminf(by2[i], by2[tid]);
                const float inter = fmaxf(1e-10f, xx2-xx1) * fmaxf(1e-10f, yy2-yy1);
                const float iou = inter / (sarea[i] + sarea[tid] - inter);
                if (iou > 0.6f) skeep[tid] = 0;
            }
        }
        __syncthreads();
    }

    if (tid < 100) {
        const bool kp = skeep[tid] != 0;
        const float q[4] = {bx1[tid], by1[tid], bx2[tid], by2[tid]};
#pragma unroll
        for (int k = 0; k < 4; ++k) {
            float v = q[k] / 1280.f;
            v = fminf(fmaxf(v, 0.f), 1.f);
            out[tid*4 + k] = kp ? v : 0.f;
        }
        out[400 + tid] = kp ? sscore[tid] : 0.f;
        out[500 + tid] = kp ? (float)slab[tid] : -1.f;
        out[600 + tid] = kp ? 1.f : 0.f;
    }
}

// ---------------------------------------------------------------------------
extern "C" void kernel_launch(void* const* d_in, const int* in_sizes, int n_in,
                              void* d_out, int out_size, void* d_ws, size_t ws_size,
                              hipStream_t stream)
{
    const float* c4  = (const float*)d_in[0];
    const float* c5  = (const float*)d_in[1];
    const float* w1a = (const float*)d_in[2];
    const float* s1a = (const float*)d_in[3];
    const float* b1a = (const float*)d_in[4];
    const float* w1b = (const float*)d_in[5];
    const float* s1b = (const float*)d_in[6];
    const float* b1b = (const float*)d_in[7];
    const float* wr  = (const float*)d_in[8];
    const float* sr  = (const float*)d_in[9];
    const float* br  = (const float*)d_in[10];
    const float* w2  = (const float*)d_in[11];
    const float* s2  = (const float*)d_in[12];
    const float* b2  = (const float*)d_in[13];
    const float* wp  = (const float*)d_in[14];
    const float* bp  = (const float*)d_in[15];

    float* ws   = (float*)d_ws;
    float* p5a  = ws;                         // 1024*1600
    float* X    = p5a + 1024*NPIX;            // 1280*1600 (concat buffer)
    float* p5c  = X + 1280*NPIX;              // 1024*1600
    float* pred = p5c + 1024*NPIX;            // 125*1600
    float* scores = pred + 125*NPIX;          // 160000
    unsigned* hist1 = (unsigned*)(scores + 160000);  // 4096
    unsigned* hist2 = hist1 + 4096;                  // 4096
    unsigned* hist3 = hist2 + 4096;                  // 256
    unsigned* meta  = hist3 + 256;                   // 16
    float*    gt_val = (float*)(meta + 16);          // 128
    unsigned* gt_idx = (unsigned*)(gt_val + 128);    // 128
    unsigned* eq_idx = gt_idx + 128;                 // 1024

    hipMemsetAsync(hist1, 0, (4096 + 4096 + 256 + 16) * sizeof(unsigned), stream);

    const dim3 g3(5, 5, 32);
    conv3x3_kernel<1024><<<g3, 256, 0, stream>>>(c5,  w1a, s1a, b1a, p5a);
    conv3x3_kernel<1024><<<g3, 256, 0, stream>>>(p5a, w1b, s1b, b1b, X + 256*NPIX);
    conv1x1_reorg_kernel<<<100, 256, 0, stream>>>(c4, wr, sr, br, X);
    conv3x3_kernel<1280><<<g3, 256, 0, stream>>>(X, w2, s2, b2, p5c);
    conv1x1_pred_kernel<<<50, 256, 0, stream>>>(p5c, wp, pred);

    score_kernel<<<32, 256, 0, stream>>>(pred, bp, scores);
    hist1_kernel<<<80, 256, 0, stream>>>(scores, hist1);
    scan_kernel<<<1, 256, 0, stream>>>(hist1, 4096, meta, 1);
    hist2_kernel<<<625, 256, 0, stream>>>(scores, meta, hist2);
    scan_kernel<<<1, 256, 0, stream>>>(hist2, 4096, meta, 2);
    hist3_kernel<<<625, 256, 0, stream>>>(scores, meta, hist3);
    scan_kernel<<<1, 256, 0, stream>>>(hist3, 256, meta, 3);
    collect_kernel<<<625, 256, 0, stream>>>(scores, meta, gt_val, gt_idx, eq_idx);
    final_kernel<<<1, 128, 0, stream>>>(pred, bp, meta, gt_val, gt_idx, eq_idx, (float*)d_out);
}

// Round 4
// 2513.844 us; speedup vs baseline: 10.0958x; 1.1040x over previous
//
#include <hip/hip_runtime.h>
#include <math.h>

#define NPIX 1600   // 40*40

typedef short  s16x8  __attribute__((ext_vector_type(8)));
typedef float  f32x16 __attribute__((ext_vector_type(16)));

__constant__ float c_aw[5] = {1.19f, 2.79f, 4.53f, 8.06f, 10.32f};
__constant__ float c_ah[5] = {1.98f, 4.59f, 8.92f, 5.29f, 10.65f};

__device__ __forceinline__ unsigned short bf16_rne(float x) {
    unsigned u = __float_as_uint(x);
    unsigned r = (u + 0x7FFFu + ((u >> 16) & 1u)) >> 16;
    return (unsigned short)r;
}
__device__ __forceinline__ float bf16_tof(unsigned short b) {
    return __uint_as_float((unsigned)b << 16);
}

// ---------------------------------------------------------------------------
// Weight pre-split: w fp32 [OC=1024][CIN][9] -> 3-term bf16 planes laid out
// [term 3][tap 9][icgrp CIN/8][oc 1024][8ic]  (16B per (oc,icgrp) run).
// Thread per (icgrp, oc), oc fastest -> b128 stores fully coalesced.
// ---------------------------------------------------------------------------
template<int CIN>
__global__ __launch_bounds__(256)
void split_w_kernel(const float* __restrict__ w, short* __restrict__ wsp)
{
    const int g   = blockIdx.x * 256 + threadIdx.x;
    const int oc  = g & 1023;
    const int icg = g >> 10;
    if (icg >= CIN / 8) return;

    float v[72];
    const float* src = w + ((size_t)oc * CIN + icg * 8) * 9;
#pragma unroll
    for (int m = 0; m < 18; ++m) {
        const float4 q = ((const float4*)src)[m];
        v[m*4+0] = q.x; v[m*4+1] = q.y; v[m*4+2] = q.z; v[m*4+3] = q.w;
    }
    const size_t ICG = CIN / 8;
#pragma unroll
    for (int tap = 0; tap < 9; ++tap) {
        unsigned short t0[8], t1[8], t2[8];
#pragma unroll
        for (int ii = 0; ii < 8; ++ii) {
            const float x = v[ii*9 + tap];
            const unsigned short b0 = bf16_rne(x);
            const float r1 = x - bf16_tof(b0);
            const unsigned short b1 = bf16_rne(r1);
            const float r2 = r1 - bf16_tof(b1);
            const unsigned short b2 = bf16_rne(r2);
            t0[ii] = b0; t1[ii] = b1; t2[ii] = b2;
        }
#pragma unroll
        for (int term = 0; term < 3; ++term) {
            const unsigned short* t = (term == 0) ? t0 : (term == 1) ? t1 : t2;
            s16x8 o;
#pragma unroll
            for (int ii = 0; ii < 8; ++ii) o[ii] = (short)t[ii];
            const size_t off = ((((size_t)term*9 + tap) * ICG + icg) * 1024 + oc) * 8;
            *(s16x8*)&wsp[off] = o;
        }
    }
}

// ---------------------------------------------------------------------------
// MFMA conv3x3 (SAME) 40x40, CIN -> 1024 oc.  Block: 64px (8x8) x 32 oc,
// 2 waves (wave wr = px half of 32). v_mfma_f32_32x32x16_bf16, bf16x3 split,
// 6 cross-products on 2 independent acc chains. Patch (10x10 x 16ic x 3 terms)
// double-buffered in LDS; B-fragments loaded straight from L2 (split planes).
// grid 800: ocb = bid&31 -> XCD affinity for weight slices.
// ---------------------------------------------------------------------------
template<int CIN>
__global__ __launch_bounds__(128)
void conv3x3_mfma(const float* __restrict__ in, const short* __restrict__ wsp,
                  const float* __restrict__ scale, const float* __restrict__ shift,
                  float* __restrict__ out)
{
    const int bid = blockIdx.x;
    const int ocb = (bid & 31) << 5;      // 32-oc slice
    const int pxt = bid >> 5;             // 0..24
    const int xt = pxt % 5, yt = pxt / 5; // 8x8 spatial tile
    const int tid  = threadIdx.x;
    const int lane = tid & 63;
    const int wr   = tid >> 6;            // wave: px half

    __shared__ short pa[2][4800];         // [buf][term 3][h 2][ppx 100][8ic]

    // per-lane A base: row = lane&31 -> (pr,pc); k-half h = lane>>5
    const int h  = lane >> 5;
    const int rr = lane & 31;
    const int pr = rr >> 3, pc = rr & 7;
    const int abase = h*800 + ((wr*4 + pr)*10 + pc) * 8;

    // per-lane B pointer part: icg-half + oc
    const short* wlane = wsp + (size_t)h*8192 + (size_t)(ocb + (lane & 31)) * 8;
    const size_t ICG = CIN / 8;

    f32x16 accA, accB;
#pragma unroll
    for (int i = 0; i < 16; ++i) { accA[i] = 0.f; accB[i] = 0.f; }

    const int y0 = yt*8 - 1, x0 = xt*8 - 1;

    auto STAGE = [&](int buf, int c0) {
        short* pb = &pa[buf][0];
        for (int e = tid; e < 1600; e += 128) {
            const int ic  = e / 100;
            const int ppx = e - ic*100;
            const int prow = ppx / 10;
            const int pcol = ppx - prow*10;
            const int gy = y0 + prow, gx = x0 + pcol;
            float x = 0.f;
            if ((unsigned)gy < 40u && (unsigned)gx < 40u)
                x = in[(size_t)(c0 + ic) * NPIX + gy*40 + gx];
            const unsigned short b0 = bf16_rne(x);
            const float r1 = x - bf16_tof(b0);
            const unsigned short b1 = bf16_rne(r1);
            const float r2 = r1 - bf16_tof(b1);
            const unsigned short b2 = bf16_rne(r2);
            short* dst = pb + (ic >> 3)*800 + ppx*8 + (ic & 7);
            dst[0]    = (short)b0;
            dst[1600] = (short)b1;
            dst[3200] = (short)b2;
        }
    };

    auto COMPUTE = [&](int buf, int icg0) {
        const short* pab = &pa[buf][0];
#pragma unroll
        for (int tap = 0; tap < 9; ++tap) {
            const int aoff = ((tap/3)*10 + (tap%3)) * 8;
            const s16x8 a0 = *(const s16x8*)(pab + abase + aoff);
            const s16x8 a1 = *(const s16x8*)(pab + 1600 + abase + aoff);
            const s16x8 a2 = *(const s16x8*)(pab + 3200 + abase + aoff);
            const s16x8 b0 = *(const s16x8*)(wlane + ((size_t)(0*9 + tap)*ICG + icg0) * 8192);
            const s16x8 b1 = *(const s16x8*)(wlane + ((size_t)(1*9 + tap)*ICG + icg0) * 8192);
            const s16x8 b2 = *(const s16x8*)(wlane + ((size_t)(2*9 + tap)*ICG + icg0) * 8192);
            accA = __builtin_amdgcn_mfma_f32_32x32x16_bf16(a0, b0, accA, 0, 0, 0);
            accB = __builtin_amdgcn_mfma_f32_32x32x16_bf16(a0, b1, accB, 0, 0, 0);
            accA = __builtin_amdgcn_mfma_f32_32x32x16_bf16(a1, b1, accA, 0, 0, 0);
            accB = __builtin_amdgcn_mfma_f32_32x32x16_bf16(a1, b0, accB, 0, 0, 0);
            accA = __builtin_amdgcn_mfma_f32_32x32x16_bf16(a2, b0, accA, 0, 0, 0);
            accB = __builtin_amdgcn_mfma_f32_32x32x16_bf16(a0, b2, accB, 0, 0, 0);
        }
    };

    const int NC = CIN / 16;
    STAGE(0, 0);
    __syncthreads();
    for (int c = 0; c < NC; ++c) {
        if (c + 1 < NC) STAGE((c + 1) & 1, (c + 1) * 16);
        COMPUTE(c & 1, 2*c);
        __syncthreads();
    }

    // epilogue: acc -> LDS transpose -> BN+lrelu -> coalesced stores
    float* eb = (float*)&pa[0][0];        // 32 x 68 floats (8.7 KB)
    const int ocl = lane & 31;
#pragma unroll
    for (int i = 0; i < 16; ++i) {
        const int rw = (i & 3) + 8*(i >> 2) + 4*h;   // D row within 32
        eb[ocl*68 + wr*32 + rw] = accA[i] + accB[i];
    }
    __syncthreads();

    const int oc2 = tid >> 2, seg = tid & 3;
    const float s  = scale[ocb + oc2];
    const float sh = shift[ocb + oc2];
#pragma unroll
    for (int q = 0; q < 2; ++q) {
        const int row = seg*2 + q;
        float4 v0 = *(float4*)&eb[oc2*68 + row*8];
        float4 v1 = *(float4*)&eb[oc2*68 + row*8 + 4];
        float t;
        t = fmaf(v0.x, s, sh); v0.x = t > 0.f ? t : 0.1f*t;
        t = fmaf(v0.y, s, sh); v0.y = t > 0.f ? t : 0.1f*t;
        t = fmaf(v0.z, s, sh); v0.z = t > 0.f ? t : 0.1f*t;
        t = fmaf(v0.w, s, sh); v0.w = t > 0.f ? t : 0.1f*t;
        t = fmaf(v1.x, s, sh); v1.x = t > 0.f ? t : 0.1f*t;
        t = fmaf(v1.y, s, sh); v1.y = t > 0.f ? t : 0.1f*t;
        t = fmaf(v1.z, s, sh); v1.z = t > 0.f ? t : 0.1f*t;
        t = fmaf(v1.w, s, sh); v1.w = t > 0.f ? t : 0.1f*t;
        float* op = out + (size_t)(ocb + oc2)*NPIX + (yt*8 + row)*40 + xt*8;
        *(float4*)op = v0;
        *(float4*)(op + 4) = v1;
    }
}

// ---------------------------------------------------------------------------
// FALLBACK fp32 conv3x3 (round-3 structure) used if ws too small for splits
// ---------------------------------------------------------------------------
template<int CIN>
__global__ __launch_bounds__(256)
void conv3x3_kernel(const float* __restrict__ in, const float* __restrict__ w,
                    const float* __restrict__ scale, const float* __restrict__ shift,
                    float* __restrict__ out)
{
    const int ox  = blockIdx.x, oy = blockIdx.y;
    const int ocb = blockIdx.z << 5;
    const int tid = threadIdx.x;
    const int tx  = tid & 15;
    const int ty  = tid >> 4;
    const int r    = ty >> 1;
    const int xoff = (ty & 1) << 2;

    __shared__ float wl[8*9*32];
    __shared__ float patch[8*10*12];

    float acc[4][2];
#pragma unroll
    for (int j = 0; j < 4; ++j) { acc[j][0] = 0.f; acc[j][1] = 0.f; }

    const int y0 = oy*8 - 1;
    const int x0 = ox*8 - 1;

    for (int c0 = 0; c0 < CIN; c0 += 8) {
        __syncthreads();
        if (tid < 64) {
            const int o  = tid >> 1;
            const int rh = (tid & 1) * 36;
            const float* wp = w + (size_t)(ocb + o)*(CIN*9) + c0*9 + rh;
#pragma unroll
            for (int m = 0; m < 9; ++m) {
                const float4 v = ((const float4*)wp)[m];
                const int rw = rh + m*4;
                wl[(rw+0)*32 + o] = v.x;
                wl[(rw+1)*32 + o] = v.y;
                wl[(rw+2)*32 + o] = v.z;
                wl[(rw+3)*32 + o] = v.w;
            }
        } else {
            const int t = tid - 64;
            for (int e = t; e < 800; e += 192) {
                const int ch  = e / 100;
                const int rem = e - ch*100;
                const int py  = rem / 10;
                const int pxx = rem - py*10;
                const int gy = y0 + py, gx = x0 + pxx;
                float v = 0.f;
                if ((unsigned)gy < 40u && (unsigned)gx < 40u)
                    v = in[(size_t)(c0+ch)*NPIX + gy*40 + gx];
                patch[ch*120 + py*12 + pxx] = v;
            }
        }
        __syncthreads();
#pragma unroll
        for (int i = 0; i < 8; ++i) {
#pragma unroll
            for (int dy = 0; dy < 3; ++dy) {
                const float* prow = &patch[i*120 + (r+dy)*12 + xoff];
                float a[6];
#pragma unroll
                for (int q = 0; q < 6; ++q) a[q] = prow[q];
#pragma unroll
                for (int dx = 0; dx < 3; ++dx) {
                    const float2 b = *(const float2*)&wl[(i*9 + dy*3 + dx)*32 + (tx<<1)];
#pragma unroll
                    for (int j = 0; j < 4; ++j) {
                        const float av = a[dx + j];
                        acc[j][0] = fmaf(av, b.x, acc[j][0]);
                        acc[j][1] = fmaf(av, b.y, acc[j][1]);
                    }
                }
            }
        }
    }

    const int gy = oy*8 + r;
    const int gx = ox*8 + xoff;
#pragma unroll
    for (int k = 0; k < 2; ++k) {
        const int oc = ocb + (tx<<1) + k;
        const float s = scale[oc], sh = shift[oc];
        float4 o4; float v;
        v = fmaf(acc[0][k], s, sh); o4.x = v > 0.f ? v : 0.1f*v;
        v = fmaf(acc[1][k], s, sh); o4.y = v > 0.f ? v : 0.1f*v;
        v = fmaf(acc[2][k], s, sh); o4.z = v > 0.f ? v : 0.1f*v;
        v = fmaf(acc[3][k], s, sh); o4.w = v > 0.f ? v : 0.1f*v;
        *(float4*)&out[(size_t)oc*NPIX + gy*40 + gx] = o4;
    }
}

// ---------------------------------------------------------------------------
// conv1x1 512->64 @80x80 + BN + lrelu + reorg(s=2), writes X channels 0..255
// ---------------------------------------------------------------------------
__global__ __launch_bounds__(256)
void conv1x1_reorg_kernel(const float* __restrict__ in, const float* __restrict__ w,
                          const float* __restrict__ scale, const float* __restrict__ shift,
                          float* __restrict__ X)
{
    const int px0 = blockIdx.x << 6;
    const int tid = threadIdx.x;
    const int tx  = tid & 15;
    const int ty  = tid >> 4;

    __shared__ float il[8*64];
    __shared__ float wlr[8*64];

    float acc[4][4];
#pragma unroll
    for (int j = 0; j < 4; ++j)
#pragma unroll
        for (int k = 0; k < 4; ++k) acc[j][k] = 0.f;

    for (int c0 = 0; c0 < 512; c0 += 8) {
        __syncthreads();
        {
            int e = tid;
#pragma unroll
            for (int q = 0; q < 2; ++q, e += 256) {
                const int ch = e >> 6, p = e & 63;
                il[ch*64 + p] = in[(size_t)(c0+ch)*6400 + px0 + p];
            }
            e = tid;
#pragma unroll
            for (int q = 0; q < 2; ++q, e += 256) {
                const int o = e >> 3, cc = e & 7;
                wlr[cc*64 + o] = w[o*512 + c0 + cc];
            }
        }
        __syncthreads();
#pragma unroll
        for (int cc = 0; cc < 8; ++cc) {
            const float4 a4 = *(const float4*)&il[cc*64 + (ty<<2)];
            const float4 b4 = *(const float4*)&wlr[cc*64 + (tx<<2)];
            const float a[4] = {a4.x, a4.y, a4.z, a4.w};
            const float b[4] = {b4.x, b4.y, b4.z, b4.w};
#pragma unroll
            for (int j = 0; j < 4; ++j)
#pragma unroll
                for (int k = 0; k < 4; ++k)
                    acc[j][k] = fmaf(a[j], b[k], acc[j][k]);
        }
    }

#pragma unroll
    for (int j = 0; j < 4; ++j) {
        const int px = px0 + (ty<<2) + j;
        const int y2 = px / 80, x2 = px - y2*80;
        const int q  = (y2 & 1)*2 + (x2 & 1);
        const int yo = y2 >> 1, xo = x2 >> 1;
#pragma unroll
        for (int k = 0; k < 4; ++k) {
            const int oc = (tx<<2) + k;
            float v = fmaf(acc[j][k], scale[oc], shift[oc]);
            v = v > 0.f ? v : 0.1f*v;
            X[(size_t)(q*64 + oc)*NPIX + yo*40 + xo] = v;
        }
    }
}

// ---------------------------------------------------------------------------
// conv1x1 1024->125 @40x40 (no bias; readers add bp)
// ---------------------------------------------------------------------------
__global__ __launch_bounds__(256)
void conv1x1_pred_kernel(const float* __restrict__ in, const float* __restrict__ w,
                         float* __restrict__ pred)
{
    const int px0 = blockIdx.x << 5;
    const int tid = threadIdx.x;
    const int tx  = tid & 15;
    const int ty  = tid >> 4;

    __shared__ float il[8*32];
    __shared__ float wlp[8*128];

    float acc[2][8];
#pragma unroll
    for (int j = 0; j < 2; ++j)
#pragma unroll
        for (int k = 0; k < 8; ++k) acc[j][k] = 0.f;

    for (int c0 = 0; c0 < 1024; c0 += 8) {
        __syncthreads();
        {
            const int ch = tid >> 5, p = tid & 31;
            il[ch*32 + p] = in[(size_t)(c0+ch)*NPIX + px0 + p];
        }
#pragma unroll
        for (int q = 0; q < 4; ++q) {
            const int e = tid + q*256;
            const int o = e >> 3, cc = e & 7;
            wlp[cc*128 + o] = (o < 125) ? w[o*1024 + c0 + cc] : 0.f;
        }
        __syncthreads();
#pragma unroll
        for (int cc = 0; cc < 8; ++cc) {
            const float a0 = il[cc*32 + (ty<<1)];
            const float a1 = il[cc*32 + (ty<<1) + 1];
            const float4 b0 = *(const float4*)&wlp[cc*128 + (tx<<3)];
            const float4 b1 = *(const float4*)&wlp[cc*128 + (tx<<3) + 4];
            const float b[8] = {b0.x,b0.y,b0.z,b0.w,b1.x,b1.y,b1.z,b1.w};
#pragma unroll
            for (int k = 0; k < 8; ++k) {
                acc[0][k] = fmaf(a0, b[k], acc[0][k]);
                acc[1][k] = fmaf(a1, b[k], acc[1][k]);
            }
        }
    }
#pragma unroll
    for (int k = 0; k < 8; ++k) {
        const int oc = (tx<<3) + k;
        if (oc < 125) {
#pragma unroll
            for (int j = 0; j < 2; ++j)
                pred[(size_t)oc*NPIX + px0 + (ty<<1) + j] = acc[j][k];
        }
    }
}

// ---------------------------------------------------------------------------
// scores = sigmoid(conf) * softmax(cls) for 8000 (px,anchor) pairs
// ---------------------------------------------------------------------------
__global__ __launch_bounds__(256)
void score_kernel(const float* __restrict__ pred, const float* __restrict__ bp,
                  float* __restrict__ scores)
{
    const int id = blockIdx.x*256 + threadIdx.x;
    if (id >= 8000) return;
    const int a  = id / 1600;
    const int px = id - a*1600;
    const float conf = pred[a*NPIX + px] + bp[a];
    float cls[20];
    float m = -INFINITY;
#pragma unroll
    for (int c = 0; c < 20; ++c) {
        cls[c] = pred[(5 + a*20 + c)*NPIX + px] + bp[5 + a*20 + c];
        m = fmaxf(m, cls[c]);
    }
    float ssum = 0.f;
#pragma unroll
    for (int c = 0; c < 20; ++c) { cls[c] = expf(cls[c] - m); ssum += cls[c]; }
    const float sig = 1.f / (1.f + expf(-conf));
    const float f = sig / ssum;
    const int base = (px*5 + a)*20;
#pragma unroll
    for (int c = 0; c < 20; ++c) scores[base + c] = cls[c] * f;
}

// ---------------------------------------------------------------------------
// exact top-100 via 3-level radix select on positive-float bits (12/12/8)
// ---------------------------------------------------------------------------
__global__ __launch_bounds__(256)
void hist1_kernel(const float* __restrict__ scores, unsigned* __restrict__ hist)
{
    __shared__ unsigned hh[4096];
    for (int i = threadIdx.x; i < 4096; i += 256) hh[i] = 0u;
    __syncthreads();
    for (int id = blockIdx.x*256 + threadIdx.x; id < 160000; id += 80*256)
        atomicAdd(&hh[__float_as_uint(scores[id]) >> 20], 1u);
    __syncthreads();
    for (int i = threadIdx.x; i < 4096; i += 256)
        if (hh[i]) atomicAdd(&hist[i], hh[i]);
}

__global__ __launch_bounds__(256)
void hist2_kernel(const float* __restrict__ scores, const unsigned* __restrict__ meta,
                  unsigned* __restrict__ hist)
{
    const int id = blockIdx.x*256 + threadIdx.x;
    if (id >= 160000) return;
    const unsigned u = __float_as_uint(scores[id]);
    if ((u >> 20) == meta[0]) atomicAdd(&hist[(u >> 8) & 0xFFFu], 1u);
}

__global__ __launch_bounds__(256)
void hist3_kernel(const float* __restrict__ scores, const unsigned* __restrict__ meta,
                  unsigned* __restrict__ hist)
{
    const int id = blockIdx.x*256 + threadIdx.x;
    if (id >= 160000) return;
    const unsigned u = __float_as_uint(scores[id]);
    const unsigned key = (meta[0] << 12) | meta[2];
    if ((u >> 8) == key) atomicAdd(&hist[u & 0xFFu], 1u);
}

__global__ __launch_bounds__(256)
void scan_kernel(const unsigned* __restrict__ hist, int nbins,
                 unsigned* __restrict__ meta, int mode)
{
    __shared__ unsigned seg[256];
    const int tid = threadIdx.x;
    const int spb = nbins >> 8;
    unsigned s = 0;
    for (int k = 0; k < spb; ++k) s += hist[tid*spb + k];
    seg[tid] = s;
    __syncthreads();
    if (tid == 0) {
        unsigned need = 100u;
        if (mode == 2) need = 100u - meta[1];
        else if (mode == 3) need = 100u - meta[3];
        unsigned cum = 0;
        int sgi = 255;
        while (sgi > 0 && cum + seg[sgi] < need) { cum += seg[sgi]; --sgi; }
        int b = sgi*spb + spb - 1;
        while (b > sgi*spb && cum + hist[b] < need) { cum += hist[b]; --b; }
        if (mode == 1)      { meta[0] = (unsigned)b; meta[1] = cum; }
        else if (mode == 2) { meta[2] = (unsigned)b; meta[3] = meta[1] + cum; }
        else {
            meta[4] = (meta[0] << 20) | (meta[2] << 8) | (unsigned)b;
            meta[5] = meta[3] + cum;
        }
    }
}

__global__ __launch_bounds__(256)
void collect_kernel(const float* __restrict__ scores, unsigned* __restrict__ meta,
                    float* __restrict__ gt_val, unsigned* __restrict__ gt_idx,
                    unsigned* __restrict__ eq_idx)
{
    const int id = blockIdx.x*256 + threadIdx.x;
    if (id >= 160000) return;
    const float v = scores[id];
    const unsigned u = __float_as_uint(v);
    const unsigned T = meta[4];
    if (u > T) {
        const unsigned p = atomicAdd(&meta[8], 1u);
        if (p < 128u) { gt_val[p] = v; gt_idx[p] = (unsigned)id; }
    } else if (u == T) {
        const unsigned p = atomicAdd(&meta[9], 1u);
        if (p < 1024u) eq_idx[p] = (unsigned)id;
    }
}

// ---------------------------------------------------------------------------
// final: assemble top-100 (stable ties), bitonic sort desc, decode, NMS, write
// ---------------------------------------------------------------------------
__global__ __launch_bounds__(128)
void final_kernel(const float* __restrict__ pred, const float* __restrict__ bp,
                  const unsigned* __restrict__ meta,
                  const float* __restrict__ gt_val, const unsigned* __restrict__ gt_idx,
                  const unsigned* __restrict__ eq_idx,
                  float* __restrict__ out)
{
    __shared__ float    sval[128];
    __shared__ unsigned sidx[128];
    __shared__ float bx1[100], by1[100], bx2[100], by2[100], sarea[100], sscore[100];
    __shared__ int   slab[100];
    __shared__ int   skeep[100];

    const int tid = threadIdx.x;
    const unsigned T    = meta[4];
    const unsigned n_gt = meta[5];
    const unsigned n_eq = meta[9] < 1024u ? meta[9] : 1024u;
    const int n_take = 100 - (int)n_gt;

    sval[tid] = -1.f;
    sidx[tid] = 0xFFFFFFFFu;
    if (tid < (int)n_gt) { sval[tid] = gt_val[tid]; sidx[tid] = gt_idx[tid]; }
    __syncthreads();
    if (tid == 0) {
        unsigned lastp1 = 0;
        const float tv = __uint_as_float(T);
        for (int t = 0; t < n_take; ++t) {
            unsigned best = 0xFFFFFFFFu;
            for (unsigned e = 0; e < n_eq; ++e) {
                const unsigned v = eq_idx[e];
                if (v >= lastp1 && v < best) best = v;
            }
            sval[n_gt + t] = tv;
            sidx[n_gt + t] = best;
            lastp1 = best + 1;
        }
    }
    __syncthreads();

    for (int k = 2; k <= 128; k <<= 1) {
        for (int j = k >> 1; j > 0; j >>= 1) {
            const int ixj = tid ^ j;
            if (ixj > tid) {
                const float v0 = sval[tid], v1 = sval[ixj];
                const unsigned i0 = sidx[tid], i1 = sidx[ixj];
                const bool prec = (v0 > v1) || (v0 == v1 && i0 < i1);
                const bool asc  = ((tid & k) == 0);
                if (asc ? !prec : prec) {
                    sval[tid] = v1; sval[ixj] = v0;
                    sidx[tid] = i1; sidx[ixj] = i0;
                }
            }
            __syncthreads();
        }
    }

    if (tid < 100) {
        const float sc = sval[tid];
        const unsigned idx = sidx[tid];
        const int ai   = (int)(idx / 20u);
        const int lab  = (int)(idx - (unsigned)ai*20u);
        const int cell = ai / 5;
        const int a    = ai - cell*5;
        const int gx = cell % 40, gy = cell / 40;
        const int rb = 105 + a*4;
        const float t0 = pred[(rb+0)*NPIX + cell] + bp[rb+0];
        const float t1 = pred[(rb+1)*NPIX + cell] + bp[rb+1];
        const float t2 = pred[(rb+2)*NPIX + cell] + bp[rb+2];
        const float t3 = pred[(rb+3)*NPIX + cell] + bp[rb+3];
        const float cx = (1.f/(1.f+expf(-t0)) + (float)gx) * 32.f;
        const float cy = (1.f/(1.f+expf(-t1)) + (float)gy) * 32.f;
        const float bw = expf(t2) * c_aw[a] * 32.f;
        const float bh = expf(t3) * c_ah[a] * 32.f;
        bx1[tid] = cx - 0.5f*bw;
        by1[tid] = cy - 0.5f*bh;
        bx2[tid] = cx + 0.5f*bw;
        by2[tid] = cy + 0.5f*bh;
        sarea[tid]  = (bx2[tid]-bx1[tid]) * (by2[tid]-by1[tid]);
        slab[tid]   = lab;
        sscore[tid] = sc;
        skeep[tid]  = (sc > 0.001f) ? 1 : 0;
    }
    __syncthreads();

    for (int i = 0; i < 99; ++i) {
        if (tid < 100 && tid > i) {
            if (skeep[i] && skeep[tid] && slab[tid] == slab[i]) {
                const float xx1 = fmaxf(bx1[i], bx1[tid]);
                const float yy1 = fmaxf(by1[i], by1[tid]);
                const float xx2 = fminf(bx2[i], bx2[tid]);
                const float yy2 = fminf(by2[i], by2[tid]);
                const float inter = fmaxf(1e-10f, xx2-xx1) * fmaxf(1e-10f, yy2-yy1);
                const float iou = inter / (sarea[i] + sarea[tid] - inter);
                if (iou > 0.6f) skeep[tid] = 0;
            }
        }
        __syncthreads();
    }

    if (tid < 100) {
        const bool kp = skeep[tid] != 0;
        const float q[4] = {bx1[tid], by1[tid], bx2[tid], by2[tid]};
#pragma unroll
        for (int k = 0; k < 4; ++k) {
            float v = q[k] / 1280.f;
            v = fminf(fmaxf(v, 0.f), 1.f);
            out[tid*4 + k] = kp ? v : 0.f;
        }
        out[400 + tid] = kp ? sscore[tid] : 0.f;
        out[500 + tid] = kp ? (float)slab[tid] : -1.f;
        out[600 + tid] = kp ? 1.f : 0.f;
    }
}

// ---------------------------------------------------------------------------
extern "C" void kernel_launch(void* const* d_in, const int* in_sizes, int n_in,
                              void* d_out, int out_size, void* d_ws, size_t ws_size,
                              hipStream_t stream)
{
    const float* c4  = (const float*)d_in[0];
    const float* c5  = (const float*)d_in[1];
    const float* w1a = (const float*)d_in[2];
    const float* s1a = (const float*)d_in[3];
    const float* b1a = (const float*)d_in[4];
    const float* w1b = (const float*)d_in[5];
    const float* s1b = (const float*)d_in[6];
    const float* b1b = (const float*)d_in[7];
    const float* wr  = (const float*)d_in[8];
    const float* sr  = (const float*)d_in[9];
    const float* br  = (const float*)d_in[10];
    const float* w2  = (const float*)d_in[11];
    const float* s2  = (const float*)d_in[12];
    const float* b2  = (const float*)d_in[13];
    const float* wp  = (const float*)d_in[14];
    const float* bp  = (const float*)d_in[15];

    float* ws   = (float*)d_ws;
    float* p5a  = ws;                                // 1024*1600
    float* X    = p5a + 1024*NPIX;                   // 1280*1600
    float* p5c  = X + 1280*NPIX;                     // 1024*1600
    float* pred = p5c + 1024*NPIX;                   // 125*1600
    float* scores = pred + 125*NPIX;                 // 160000
    unsigned* hist1 = (unsigned*)(scores + 160000);  // 4096
    unsigned* hist2 = hist1 + 4096;                  // 4096
    unsigned* hist3 = hist2 + 4096;                  // 256
    unsigned* meta  = hist3 + 256;                   // 16
    float*    gt_val = (float*)(meta + 16);          // 128
    unsigned* gt_idx = (unsigned*)(gt_val + 128);    // 128
    unsigned* eq_idx = gt_idx + 128;                 // 1024

    // bf16 split-weight planes (aligned after the fp32 region)
    size_t base_shorts = (size_t)(((char*)(eq_idx + 1024) - (char*)d_ws + 255) & ~255ull) / 2;
    short* wsbase = (short*)d_ws;
    const size_t W1AS = (size_t)3*9*128*1024*8;      // 28,311,552 shorts (CIN=1024)
    const size_t W2S  = (size_t)3*9*160*1024*8;      // 35,389,440 shorts (CIN=1280)
    short* w1as = wsbase + base_shorts;
    short* w1bs = w1as + W1AS;
    short* w2s  = w1bs + W1AS;
    const size_t WS_NEEDED = (base_shorts + W1AS + W1AS + W2S) * 2;
    const bool use_mfma = (ws_size >= WS_NEEDED);

    hipMemsetAsync(hist1, 0, (4096 + 4096 + 256 + 16) * sizeof(unsigned), stream);

    if (use_mfma) {
        split_w_kernel<1024><<<512, 256, 0, stream>>>(w1a, w1as);
        split_w_kernel<1024><<<512, 256, 0, stream>>>(w1b, w1bs);
        split_w_kernel<1280><<<640, 256, 0, stream>>>(w2,  w2s);

        conv3x3_mfma<1024><<<800, 128, 0, stream>>>(c5,  w1as, s1a, b1a, p5a);
        conv3x3_mfma<1024><<<800, 128, 0, stream>>>(p5a, w1bs, s1b, b1b, X + 256*NPIX);
        conv1x1_reorg_kernel<<<100, 256, 0, stream>>>(c4, wr, sr, br, X);
        conv3x3_mfma<1280><<<800, 128, 0, stream>>>(X, w2s, s2, b2, p5c);
    } else {
        const dim3 g3(5, 5, 32);
        conv3x3_kernel<1024><<<g3, 256, 0, stream>>>(c5,  w1a, s1a, b1a, p5a);
        conv3x3_kernel<1024><<<g3, 256, 0, stream>>>(p5a, w1b, s1b, b1b, X + 256*NPIX);
        conv1x1_reorg_kernel<<<100, 256, 0, stream>>>(c4, wr, sr, br, X);
        conv3x3_kernel<1280><<<g3, 256, 0, stream>>>(X, w2, s2, b2, p5c);
    }

    conv1x1_pred_kernel<<<50, 256, 0, stream>>>(p5c, wp, pred);

    score_kernel<<<32, 256, 0, stream>>>(pred, bp, scores);
    hist1_kernel<<<80, 256, 0, stream>>>(scores, hist1);
    scan_kernel<<<1, 256, 0, stream>>>(hist1, 4096, meta, 1);
    hist2_kernel<<<625, 256, 0, stream>>>(scores, meta, hist2);
    scan_kernel<<<1, 256, 0, stream>>>(hist2, 4096, meta, 2);
    hist3_kernel<<<625, 256, 0, stream>>>(scores, meta, hist3);
    scan_kernel<<<1, 256, 0, stream>>>(hist3, 256, meta, 3);
    collect_kernel<<<625, 256, 0, stream>>>(scores, meta, gt_val, gt_idx, eq_idx);
    final_kernel<<<1, 128, 0, stream>>>(pred, bp, meta, gt_val, gt_idx, eq_idx, (float*)d_out);
}

// Round 5
// 1646.145 us; speedup vs baseline: 15.4173x; 1.5271x over previous
//
#include <hip/hip_runtime.h>
#include <math.h>

#define NPIX 1600   // 40*40

typedef short  s16x8  __attribute__((ext_vector_type(8)));
typedef float  f32x16 __attribute__((ext_vector_type(16)));

typedef const __attribute__((address_space(1))) void gas_t;
typedef __attribute__((address_space(3))) void las_t;
#define GLL16(g, l) __builtin_amdgcn_global_load_lds((gas_t*)(g), (las_t*)(l), 16, 0, 0)

__constant__ float c_aw[5] = {1.19f, 2.79f, 4.53f, 8.06f, 10.32f};
__constant__ float c_ah[5] = {1.98f, 4.59f, 8.92f, 5.29f, 10.65f};

__device__ __forceinline__ unsigned short bf16_rne(float x) {
    unsigned u = __float_as_uint(x);
    unsigned r = (u + 0x7FFFu + ((u >> 16) & 1u)) >> 16;
    return (unsigned short)r;
}
__device__ __forceinline__ float bf16_tof(unsigned short b) {
    return __uint_as_float((unsigned)b << 16);
}

// ---------------------------------------------------------------------------
// Weight pre-split: fp32 [1024][CIN][9] -> bf16x3 planes [term][tap][icg][oc][8ic]
// ---------------------------------------------------------------------------
template<int CIN>
__global__ __launch_bounds__(256)
void split_w_kernel(const float* __restrict__ w, short* __restrict__ wsp)
{
    const int g   = blockIdx.x * 256 + threadIdx.x;
    const int oc  = g & 1023;
    const int icg = g >> 10;
    if (icg >= CIN / 8) return;

    float v[72];
    const float* src = w + ((size_t)oc * CIN + icg * 8) * 9;
#pragma unroll
    for (int m = 0; m < 18; ++m) {
        const float4 q = ((const float4*)src)[m];
        v[m*4+0] = q.x; v[m*4+1] = q.y; v[m*4+2] = q.z; v[m*4+3] = q.w;
    }
    const size_t ICG = CIN / 8;
#pragma unroll
    for (int tap = 0; tap < 9; ++tap) {
        s16x8 t0, t1, t2;
#pragma unroll
        for (int ii = 0; ii < 8; ++ii) {
            const float x = v[ii*9 + tap];
            const unsigned short b0 = bf16_rne(x);
            const float r1 = x - bf16_tof(b0);
            const unsigned short b1 = bf16_rne(r1);
            const float r2 = r1 - bf16_tof(b1);
            const unsigned short b2 = bf16_rne(r2);
            t0[ii] = (short)b0; t1[ii] = (short)b1; t2[ii] = (short)b2;
        }
        const size_t base = (((size_t)tap * ICG + icg) * 1024 + oc) * 8;
        const size_t tstr = (size_t)9 * ICG * 1024 * 8;
        *(s16x8*)&wsp[base]          = t0;
        *(s16x8*)&wsp[base + tstr]   = t1;
        *(s16x8*)&wsp[base + 2*tstr] = t2;
    }
}

// ---------------------------------------------------------------------------
// Activation pre-split: fp32 [CIN][40][40] -> padded bf16x3 planes
// [term][icg][42][42][8ic], zero borders (buffer pre-zeroed by memset).
// ---------------------------------------------------------------------------
template<int CIN>
__global__ __launch_bounds__(256)
void split_a_kernel(const float* __restrict__ in, short* __restrict__ ap)
{
    constexpr int ICG = CIN / 8;
    const int id  = blockIdx.x * 256 + threadIdx.x;    // icg*1600 + px
    const int icg = id / 1600;
    const int px  = id - icg * 1600;
    if (icg >= ICG) return;
    const int py = px / 40, pxx = px - py*40;

    s16x8 o0, o1, o2;
#pragma unroll
    for (int ii = 0; ii < 8; ++ii) {
        const float x = in[(size_t)(icg*8 + ii) * NPIX + px];
        const unsigned short b0 = bf16_rne(x);
        const float r1 = x - bf16_tof(b0);
        const unsigned short b1 = bf16_rne(r1);
        const float r2 = r1 - bf16_tof(b1);
        const unsigned short b2 = bf16_rne(r2);
        o0[ii] = (short)b0; o1[ii] = (short)b1; o2[ii] = (short)b2;
    }
    const size_t dst  = ((size_t)icg * 1764 + (py+1)*42 + (pxx+1)) * 8;
    const size_t tstr = (size_t)ICG * 1764 * 8;
    *(s16x8*)&ap[dst]          = o0;
    *(s16x8*)&ap[dst + tstr]   = o1;
    *(s16x8*)&ap[dst + 2*tstr] = o2;
}

// ---------------------------------------------------------------------------
// MFMA conv3x3 v2: 1-wave blocks (64 thr), wave tile 64px(8x8) x 64oc,
// K-split over blockIdx.z (32 icg = 16 chunks of 16ic each).
// A: pre-split planes -> LDS via global_load_lds, double-buffered, counted vmcnt.
// B: pre-split planes direct from L2, 2-deep tap prefetch.
// acc: 4 x f32x16 (2x2 subtiles of 32x32). 6 cross-products (bf16x3).
// Partials (fp32) -> part[ks][px][oc] fully coalesced; reduced later.
// ---------------------------------------------------------------------------
template<int CIN>
__global__ __launch_bounds__(64, 2)
void conv3x3_mfma2(const short* __restrict__ ap, const short* __restrict__ wsp,
                   float* __restrict__ part)
{
    constexpr int ICG = CIN / 8;
    const int pxt = blockIdx.x;                 // 0..24
    const int xt = pxt % 5, yt = pxt / 5;
    const int ocb = blockIdx.y << 6;            // 64 oc
    const int ks  = blockIdx.z;
    const int lane = threadIdx.x;

    __shared__ __align__(16) short Abuf[2][9600];   // [buf][(t*2+h)*1600 + ppx*8]

    const int rr = lane & 31;
    const int h  = lane >> 5;

    // per-lane staging source offsets (in shorts); patch = 10x10 at (yt*8-1, xt*8-1)
    const int pr1 = lane / 10,     pc1 = lane - pr1*10;
    const int l2n = lane + 64;
    const int pr2 = l2n / 10,      pc2 = l2n - pr2*10;
    const size_t go1 = ((size_t)((yt*8 + pr1)*42 + xt*8 + pc1)) * 8;
    const size_t go2 = ((size_t)((yt*8 + pr2)*42 + xt*8 + pc2)) * 8;

    // compute-lane constants: A patch index of this lane's px (m-subtile 0 / 1)
    const int pb0 = (rr >> 3)*10 + (rr & 7);
    const int pb1 = pb0 + 40;
    const short* pB = wsp + (size_t)h*8192 + (size_t)(ocb + rr)*8;

    f32x16 acc[2][2];
#pragma unroll
    for (int m2 = 0; m2 < 2; ++m2)
#pragma unroll
        for (int n2 = 0; n2 < 2; ++n2)
#pragma unroll
            for (int i = 0; i < 16; ++i) acc[m2][n2][i] = 0.f;

    const int icgS = ks * 32;

    auto STAGE = [&](int buf, int icg0) {
#pragma unroll
        for (int t = 0; t < 3; ++t)
#pragma unroll
            for (int hh = 0; hh < 2; ++hh) {
                const short* g = ap + (size_t)(t*ICG + icg0 + hh) * (1764*8);
                short* l = &Abuf[buf][(t*2 + hh)*1600];
                GLL16(g + go1, l);
                if (lane < 36) GLL16(g + go2, l + 512);
            }
    };

    auto CHUNK = [&](int buf, int icg0) {
        const short* AB = &Abuf[buf][h*1600];
        const size_t bco = (size_t)icg0 * 8192;
        s16x8 a[3][2];
        s16x8 bb[2][3][2];
#pragma unroll
        for (int t = 0; t < 3; ++t)
#pragma unroll
            for (int n2 = 0; n2 < 2; ++n2)
                bb[0][t][n2] = *(const s16x8*)(pB + ((size_t)(t*9)*ICG)*8192 + bco + n2*256);

#pragma unroll
        for (int tap = 0; tap < 9; ++tap) {
            const int dy = tap / 3, dx = tap - dy*3;
#pragma unroll
            for (int t = 0; t < 3; ++t) {
                a[t][0] = *(const s16x8*)(AB + (size_t)t*3200 + (size_t)(pb0 + dy*10 + dx)*8);
                a[t][1] = *(const s16x8*)(AB + (size_t)t*3200 + (size_t)(pb1 + dy*10 + dx)*8);
            }
            if (tap < 8) {
#pragma unroll
                for (int t = 0; t < 3; ++t)
#pragma unroll
                    for (int n2 = 0; n2 < 2; ++n2)
                        bb[(tap+1)&1][t][n2] =
                            *(const s16x8*)(pB + ((size_t)(t*9 + tap+1)*ICG)*8192 + bco + n2*256);
            }
            constexpr int PA6[6] = {0,0,1,1,2,0};
            constexpr int PB6[6] = {0,1,0,1,0,2};
#pragma unroll
            for (int p = 0; p < 6; ++p)
#pragma unroll
                for (int m2 = 0; m2 < 2; ++m2)
#pragma unroll
                    for (int n2 = 0; n2 < 2; ++n2)
                        acc[m2][n2] = __builtin_amdgcn_mfma_f32_32x32x16_bf16(
                            a[PA6[p]][m2], bb[tap&1][PB6[p]][n2], acc[m2][n2], 0, 0, 0);
        }
    };

    STAGE(0, icgS);
    for (int c = 0; c < 16; ++c) {
        if (c < 15) {
            STAGE((c+1) & 1, icgS + 2*(c+1));
            asm volatile("s_waitcnt vmcnt(12)" ::: "memory");   // chunk-c stage done; c+1 in flight
        } else {
            asm volatile("s_waitcnt vmcnt(0)" ::: "memory");
        }
        __builtin_amdgcn_sched_barrier(0);
        CHUNK(c & 1, icgS + 2*c);
    }

    // epilogue: coalesced partial stores, layout part[ks][px][oc]
    float* pbase = part + (size_t)ks * (1600*1024);
#pragma unroll
    for (int m2 = 0; m2 < 2; ++m2)
#pragma unroll
        for (int n2 = 0; n2 < 2; ++n2)
#pragma unroll
            for (int i = 0; i < 16; ++i) {
                const int row = (i & 3) + 8*(i >> 2) + 4*h;     // 0..31 (px within subtile)
                const int pxl = m2*32 + row;                     // 0..63
                const int pxg = (yt*8 + (pxl >> 3))*40 + xt*8 + (pxl & 7);
                pbase[(size_t)pxg*1024 + ocb + n2*32 + rr] = acc[m2][n2][i];
            }
}

// ---------------------------------------------------------------------------
// reduce partials (fixed order) + BN + leaky ReLU -> fp32 [oc][px]
// ---------------------------------------------------------------------------
__global__ __launch_bounds__(256)
void reduce_bn_kernel(const float* __restrict__ part, const int KS,
                      const float* __restrict__ scale, const float* __restrict__ shift,
                      float* __restrict__ out)
{
    const int pxt = blockIdx.x;
    const int xt = pxt % 5, yt = pxt / 5;
    const int ocb = blockIdx.y << 6;
    const int t = threadIdx.x;
    __shared__ float eb[64*72];

    float s[16];
#pragma unroll
    for (int j = 0; j < 16; ++j) s[j] = 0.f;
    for (int ks = 0; ks < KS; ++ks) {
        const float* pb = part + (size_t)ks * (1600*1024);
#pragma unroll
        for (int j = 0; j < 16; ++j) {
            const int e = t + j*256;
            const int pxl = e >> 6, ocl = e & 63;
            const int pxg = (yt*8 + (pxl >> 3))*40 + xt*8 + (pxl & 7);
            s[j] += pb[(size_t)pxg*1024 + ocb + ocl];
        }
    }
#pragma unroll
    for (int j = 0; j < 16; ++j) {
        const int e = t + j*256;
        const int pxl = e >> 6, ocl = e & 63;
        float v = fmaf(s[j], scale[ocb+ocl], shift[ocb+ocl]);
        eb[ocl*72 + pxl] = v > 0.f ? v : 0.1f*v;
    }
    __syncthreads();
    const int ocl = t >> 2, seg = t & 3;
#pragma unroll
    for (int q = 0; q < 2; ++q) {
        const int rw = seg*2 + q;
        float4 v0 = *(float4*)&eb[ocl*72 + rw*8];
        float4 v1 = *(float4*)&eb[ocl*72 + rw*8 + 4];
        float* op = out + (size_t)(ocb + ocl)*NPIX + (yt*8 + rw)*40 + xt*8;
        *(float4*)op = v0;
        *(float4*)(op + 4) = v1;
    }
}

// ---------------------------------------------------------------------------
// FALLBACK fp32 conv3x3 (round-3 structure) used if ws too small
// ---------------------------------------------------------------------------
template<int CIN>
__global__ __launch_bounds__(256)
void conv3x3_kernel(const float* __restrict__ in, const float* __restrict__ w,
                    const float* __restrict__ scale, const float* __restrict__ shift,
                    float* __restrict__ out)
{
    const int ox  = blockIdx.x, oy = blockIdx.y;
    const int ocb = blockIdx.z << 5;
    const int tid = threadIdx.x;
    const int tx  = tid & 15;
    const int ty  = tid >> 4;
    const int r    = ty >> 1;
    const int xoff = (ty & 1) << 2;

    __shared__ float wl[8*9*32];
    __shared__ float patch[8*10*12];

    float acc[4][2];
#pragma unroll
    for (int j = 0; j < 4; ++j) { acc[j][0] = 0.f; acc[j][1] = 0.f; }

    const int y0 = oy*8 - 1;
    const int x0 = ox*8 - 1;

    for (int c0 = 0; c0 < CIN; c0 += 8) {
        __syncthreads();
        if (tid < 64) {
            const int o  = tid >> 1;
            const int rh = (tid & 1) * 36;
            const float* wp = w + (size_t)(ocb + o)*(CIN*9) + c0*9 + rh;
#pragma unroll
            for (int m = 0; m < 9; ++m) {
                const float4 v = ((const float4*)wp)[m];
                const int rw = rh + m*4;
                wl[(rw+0)*32 + o] = v.x;
                wl[(rw+1)*32 + o] = v.y;
                wl[(rw+2)*32 + o] = v.z;
                wl[(rw+3)*32 + o] = v.w;
            }
        } else {
            const int t = tid - 64;
            for (int e = t; e < 800; e += 192) {
                const int ch  = e / 100;
                const int rem = e - ch*100;
                const int py  = rem / 10;
                const int pxx = rem - py*10;
                const int gy = y0 + py, gx = x0 + pxx;
                float v = 0.f;
                if ((unsigned)gy < 40u && (unsigned)gx < 40u)
                    v = in[(size_t)(c0+ch)*NPIX + gy*40 + gx];
                patch[ch*120 + py*12 + pxx] = v;
            }
        }
        __syncthreads();
#pragma unroll
        for (int i = 0; i < 8; ++i) {
#pragma unroll
            for (int dy = 0; dy < 3; ++dy) {
                const float* prow = &patch[i*120 + (r+dy)*12 + xoff];
                float a[6];
#pragma unroll
                for (int q = 0; q < 6; ++q) a[q] = prow[q];
#pragma unroll
                for (int dx = 0; dx < 3; ++dx) {
                    const float2 b = *(const float2*)&wl[(i*9 + dy*3 + dx)*32 + (tx<<1)];
#pragma unroll
                    for (int j = 0; j < 4; ++j) {
                        const float av = a[dx + j];
                        acc[j][0] = fmaf(av, b.x, acc[j][0]);
                        acc[j][1] = fmaf(av, b.y, acc[j][1]);
                    }
                }
            }
        }
    }

    const int gy = oy*8 + r;
    const int gx = ox*8 + xoff;
#pragma unroll
    for (int k = 0; k < 2; ++k) {
        const int oc = ocb + (tx<<1) + k;
        const float s = scale[oc], sh = shift[oc];
        float4 o4; float v;
        v = fmaf(acc[0][k], s, sh); o4.x = v > 0.f ? v : 0.1f*v;
        v = fmaf(acc[1][k], s, sh); o4.y = v > 0.f ? v : 0.1f*v;
        v = fmaf(acc[2][k], s, sh); o4.z = v > 0.f ? v : 0.1f*v;
        v = fmaf(acc[3][k], s, sh); o4.w = v > 0.f ? v : 0.1f*v;
        *(float4*)&out[(size_t)oc*NPIX + gy*40 + gx] = o4;
    }
}

// ---------------------------------------------------------------------------
// conv1x1 512->64 @80x80 + BN + lrelu + reorg(s=2), writes X channels 0..255
// ---------------------------------------------------------------------------
__global__ __launch_bounds__(256)
void conv1x1_reorg_kernel(const float* __restrict__ in, const float* __restrict__ w,
                          const float* __restrict__ scale, const float* __restrict__ shift,
                          float* __restrict__ X)
{
    const int px0 = blockIdx.x << 6;
    const int tid = threadIdx.x;
    const int tx  = tid & 15;
    const int ty  = tid >> 4;

    __shared__ float il[8*64];
    __shared__ float wlr[8*64];

    float acc[4][4];
#pragma unroll
    for (int j = 0; j < 4; ++j)
#pragma unroll
        for (int k = 0; k < 4; ++k) acc[j][k] = 0.f;

    for (int c0 = 0; c0 < 512; c0 += 8) {
        __syncthreads();
        {
            int e = tid;
#pragma unroll
            for (int q = 0; q < 2; ++q, e += 256) {
                const int ch = e >> 6, p = e & 63;
                il[ch*64 + p] = in[(size_t)(c0+ch)*6400 + px0 + p];
            }
            e = tid;
#pragma unroll
            for (int q = 0; q < 2; ++q, e += 256) {
                const int o = e >> 3, cc = e & 7;
                wlr[cc*64 + o] = w[o*512 + c0 + cc];
            }
        }
        __syncthreads();
#pragma unroll
        for (int cc = 0; cc < 8; ++cc) {
            const float4 a4 = *(const float4*)&il[cc*64 + (ty<<2)];
            const float4 b4 = *(const float4*)&wlr[cc*64 + (tx<<2)];
            const float a[4] = {a4.x, a4.y, a4.z, a4.w};
            const float b[4] = {b4.x, b4.y, b4.z, b4.w};
#pragma unroll
            for (int j = 0; j < 4; ++j)
#pragma unroll
                for (int k = 0; k < 4; ++k)
                    acc[j][k] = fmaf(a[j], b[k], acc[j][k]);
        }
    }

#pragma unroll
    for (int j = 0; j < 4; ++j) {
        const int px = px0 + (ty<<2) + j;
        const int y2 = px / 80, x2 = px - y2*80;
        const int q  = (y2 & 1)*2 + (x2 & 1);
        const int yo = y2 >> 1, xo = x2 >> 1;
#pragma unroll
        for (int k = 0; k < 4; ++k) {
            const int oc = (tx<<2) + k;
            float v = fmaf(acc[j][k], scale[oc], shift[oc]);
            v = v > 0.f ? v : 0.1f*v;
            X[(size_t)(q*64 + oc)*NPIX + yo*40 + xo] = v;
        }
    }
}

// ---------------------------------------------------------------------------
// conv1x1 1024->125 @40x40 (no bias; readers add bp)
// ---------------------------------------------------------------------------
__global__ __launch_bounds__(256)
void conv1x1_pred_kernel(const float* __restrict__ in, const float* __restrict__ w,
                         float* __restrict__ pred)
{
    const int px0 = blockIdx.x << 5;
    const int tid = threadIdx.x;
    const int tx  = tid & 15;
    const int ty  = tid >> 4;

    __shared__ float il[8*32];
    __shared__ float wlp[8*128];

    float acc[2][8];
#pragma unroll
    for (int j = 0; j < 2; ++j)
#pragma unroll
        for (int k = 0; k < 8; ++k) acc[j][k] = 0.f;

    for (int c0 = 0; c0 < 1024; c0 += 8) {
        __syncthreads();
        {
            const int ch = tid >> 5, p = tid & 31;
            il[ch*32 + p] = in[(size_t)(c0+ch)*NPIX + px0 + p];
        }
#pragma unroll
        for (int q = 0; q < 4; ++q) {
            const int e = tid + q*256;
            const int o = e >> 3, cc = e & 7;
            wlp[cc*128 + o] = (o < 125) ? w[o*1024 + c0 + cc] : 0.f;
        }
        __syncthreads();
#pragma unroll
        for (int cc = 0; cc < 8; ++cc) {
            const float a0 = il[cc*32 + (ty<<1)];
            const float a1 = il[cc*32 + (ty<<1) + 1];
            const float4 b0 = *(const float4*)&wlp[cc*128 + (tx<<3)];
            const float4 b1 = *(const float4*)&wlp[cc*128 + (tx<<3) + 4];
            const float b[8] = {b0.x,b0.y,b0.z,b0.w,b1.x,b1.y,b1.z,b1.w};
#pragma unroll
            for (int k = 0; k < 8; ++k) {
                acc[0][k] = fmaf(a0, b[k], acc[0][k]);
                acc[1][k] = fmaf(a1, b[k], acc[1][k]);
            }
        }
    }
#pragma unroll
    for (int k = 0; k < 8; ++k) {
        const int oc = (tx<<3) + k;
        if (oc < 125) {
#pragma unroll
            for (int j = 0; j < 2; ++j)
                pred[(size_t)oc*NPIX + px0 + (ty<<1) + j] = acc[j][k];
        }
    }
}

// ---------------------------------------------------------------------------
// scores = sigmoid(conf) * softmax(cls) for 8000 (px,anchor) pairs
// ---------------------------------------------------------------------------
__global__ __launch_bounds__(256)
void score_kernel(const float* __restrict__ pred, const float* __restrict__ bp,
                  float* __restrict__ scores)
{
    const int id = blockIdx.x*256 + threadIdx.x;
    if (id >= 8000) return;
    const int a  = id / 1600;
    const int px = id - a*1600;
    const float conf = pred[a*NPIX + px] + bp[a];
    float cls[20];
    float m = -INFINITY;
#pragma unroll
    for (int c = 0; c < 20; ++c) {
        cls[c] = pred[(5 + a*20 + c)*NPIX + px] + bp[5 + a*20 + c];
        m = fmaxf(m, cls[c]);
    }
    float ssum = 0.f;
#pragma unroll
    for (int c = 0; c < 20; ++c) { cls[c] = expf(cls[c] - m); ssum += cls[c]; }
    const float sig = 1.f / (1.f + expf(-conf));
    const float f = sig / ssum;
    const int base = (px*5 + a)*20;
#pragma unroll
    for (int c = 0; c < 20; ++c) scores[base + c] = cls[c] * f;
}

// ---------------------------------------------------------------------------
// exact top-100 via 3-level radix select on positive-float bits (12/12/8)
// ---------------------------------------------------------------------------
__global__ __launch_bounds__(256)
void hist1_kernel(const float* __restrict__ scores, unsigned* __restrict__ hist)
{
    __shared__ unsigned hh[4096];
    for (int i = threadIdx.x; i < 4096; i += 256) hh[i] = 0u;
    __syncthreads();
    for (int id = blockIdx.x*256 + threadIdx.x; id < 160000; id += 80*256)
        atomicAdd(&hh[__float_as_uint(scores[id]) >> 20], 1u);
    __syncthreads();
    for (int i = threadIdx.x; i < 4096; i += 256)
        if (hh[i]) atomicAdd(&hist[i], hh[i]);
}

__global__ __launch_bounds__(256)
void hist2_kernel(const float* __restrict__ scores, const unsigned* __restrict__ meta,
                  unsigned* __restrict__ hist)
{
    const int id = blockIdx.x*256 + threadIdx.x;
    if (id >= 160000) return;
    const unsigned u = __float_as_uint(scores[id]);
    if ((u >> 20) == meta[0]) atomicAdd(&hist[(u >> 8) & 0xFFFu], 1u);
}

__global__ __launch_bounds__(256)
void hist3_kernel(const float* __restrict__ scores, const unsigned* __restrict__ meta,
                  unsigned* __restrict__ hist)
{
    const int id = blockIdx.x*256 + threadIdx.x;
    if (id >= 160000) return;
    const unsigned u = __float_as_uint(scores[id]);
    const unsigned key = (meta[0] << 12) | meta[2];
    if ((u >> 8) == key) atomicAdd(&hist[u & 0xFFu], 1u);
}

__global__ __launch_bounds__(256)
void scan_kernel(const unsigned* __restrict__ hist, int nbins,
                 unsigned* __restrict__ meta, int mode)
{
    __shared__ unsigned seg[256];
    const int tid = threadIdx.x;
    const int spb = nbins >> 8;
    unsigned s = 0;
    for (int k = 0; k < spb; ++k) s += hist[tid*spb + k];
    seg[tid] = s;
    __syncthreads();
    if (tid == 0) {
        unsigned need = 100u;
        if (mode == 2) need = 100u - meta[1];
        else if (mode == 3) need = 100u - meta[3];
        unsigned cum = 0;
        int sgi = 255;
        while (sgi > 0 && cum + seg[sgi] < need) { cum += seg[sgi]; --sgi; }
        int b = sgi*spb + spb - 1;
        while (b > sgi*spb && cum + hist[b] < need) { cum += hist[b]; --b; }
        if (mode == 1)      { meta[0] = (unsigned)b; meta[1] = cum; }
        else if (mode == 2) { meta[2] = (unsigned)b; meta[3] = meta[1] + cum; }
        else {
            meta[4] = (meta[0] << 20) | (meta[2] << 8) | (unsigned)b;
            meta[5] = meta[3] + cum;
        }
    }
}

__global__ __launch_bounds__(256)
void collect_kernel(const float* __restrict__ scores, unsigned* __restrict__ meta,
                    float* __restrict__ gt_val, unsigned* __restrict__ gt_idx,
                    unsigned* __restrict__ eq_idx)
{
    const int id = blockIdx.x*256 + threadIdx.x;
    if (id >= 160000) return;
    const float v = scores[id];
    const unsigned u = __float_as_uint(v);
    const unsigned T = meta[4];
    if (u > T) {
        const unsigned p = atomicAdd(&meta[8], 1u);
        if (p < 128u) { gt_val[p] = v; gt_idx[p] = (unsigned)id; }
    } else if (u == T) {
        const unsigned p = atomicAdd(&meta[9], 1u);
        if (p < 1024u) eq_idx[p] = (unsigned)id;
    }
}

// ---------------------------------------------------------------------------
// final: assemble top-100 (stable ties), bitonic sort desc, decode, NMS, write
// ---------------------------------------------------------------------------
__global__ __launch_bounds__(128)
void final_kernel(const float* __restrict__ pred, const float* __restrict__ bp,
                  const unsigned* __restrict__ meta,
                  const float* __restrict__ gt_val, const unsigned* __restrict__ gt_idx,
                  const unsigned* __restrict__ eq_idx,
                  float* __restrict__ out)
{
    __shared__ float    sval[128];
    __shared__ unsigned sidx[128];
    __shared__ float bx1[100], by1[100], bx2[100], by2[100], sarea[100], sscore[100];
    __shared__ int   slab[100];
    __shared__ int   skeep[100];

    const int tid = threadIdx.x;
    const unsigned T    = meta[4];
    const unsigned n_gt = meta[5];
    const unsigned n_eq = meta[9] < 1024u ? meta[9] : 1024u;
    const int n_take = 100 - (int)n_gt;

    sval[tid] = -1.f;
    sidx[tid] = 0xFFFFFFFFu;
    if (tid < (int)n_gt) { sval[tid] = gt_val[tid]; sidx[tid] = gt_idx[tid]; }
    __syncthreads();
    if (tid == 0) {
        unsigned lastp1 = 0;
        const float tv = __uint_as_float(T);
        for (int t = 0; t < n_take; ++t) {
            unsigned best = 0xFFFFFFFFu;
            for (unsigned e = 0; e < n_eq; ++e) {
                const unsigned v = eq_idx[e];
                if (v >= lastp1 && v < best) best = v;
            }
            sval[n_gt + t] = tv;
            sidx[n_gt + t] = best;
            lastp1 = best + 1;
        }
    }
    __syncthreads();

    for (int k = 2; k <= 128; k <<= 1) {
        for (int j = k >> 1; j > 0; j >>= 1) {
            const int ixj = tid ^ j;
            if (ixj > tid) {
                const float v0 = sval[tid], v1 = sval[ixj];
                const unsigned i0 = sidx[tid], i1 = sidx[ixj];
                const bool prec = (v0 > v1) || (v0 == v1 && i0 < i1);
                const bool asc  = ((tid & k) == 0);
                if (asc ? !prec : prec) {
                    sval[tid] = v1; sval[ixj] = v0;
                    sidx[tid] = i1; sidx[ixj] = i0;
                }
            }
            __syncthreads();
        }
    }

    if (tid < 100) {
        const float sc = sval[tid];
        const unsigned idx = sidx[tid];
        const int ai   = (int)(idx / 20u);
        const int lab  = (int)(idx - (unsigned)ai*20u);
        const int cell = ai / 5;
        const int a    = ai - cell*5;
        const int gx = cell % 40, gy = cell / 40;
        const int rb = 105 + a*4;
        const float t0 = pred[(rb+0)*NPIX + cell] + bp[rb+0];
        const float t1 = pred[(rb+1)*NPIX + cell] + bp[rb+1];
        const float t2 = pred[(rb+2)*NPIX + cell] + bp[rb+2];
        const float t3 = pred[(rb+3)*NPIX + cell] + bp[rb+3];
        const float cx = (1.f/(1.f+expf(-t0)) + (float)gx) * 32.f;
        const float cy = (1.f/(1.f+expf(-t1)) + (float)gy) * 32.f;
        const float bw = expf(t2) * c_aw[a] * 32.f;
        const float bh = expf(t3) * c_ah[a] * 32.f;
        bx1[tid] = cx - 0.5f*bw;
        by1[tid] = cy - 0.5f*bh;
        bx2[tid] = cx + 0.5f*bw;
        by2[tid] = cy + 0.5f*bh;
        sarea[tid]  = (bx2[tid]-bx1[tid]) * (by2[tid]-by1[tid]);
        slab[tid]   = lab;
        sscore[tid] = sc;
        skeep[tid]  = (sc > 0.001f) ? 1 : 0;
    }
    __syncthreads();

    for (int i = 0; i < 99; ++i) {
        if (tid < 100 && tid > i) {
            if (skeep[i] && skeep[tid] && slab[tid] == slab[i]) {
                const float xx1 = fmaxf(bx1[i], bx1[tid]);
                const float yy1 = fmaxf(by1[i], by1[tid]);
                const float xx2 = fminf(bx2[i], bx2[tid]);
                const float yy2 = fminf(by2[i], by2[tid]);
                const float inter = fmaxf(1e-10f, xx2-xx1) * fmaxf(1e-10f, yy2-yy1);
                const float iou = inter / (sarea[i] + sarea[tid] - inter);
                if (iou > 0.6f) skeep[tid] = 0;
            }
        }
        __syncthreads();
    }

    if (tid < 100) {
        const bool kp = skeep[tid] != 0;
        const float q[4] = {bx1[tid], by1[tid], bx2[tid], by2[tid]};
#pragma unroll
        for (int k = 0; k < 4; ++k) {
            float v = q[k] / 1280.f;
            v = fminf(fmaxf(v, 0.f), 1.f);
            out[tid*4 + k] = kp ? v : 0.f;
        }
        out[400 + tid] = kp ? sscore[tid] : 0.f;
        out[500 + tid] = kp ? (float)slab[tid] : -1.f;
        out[600 + tid] = kp ? 1.f : 0.f;
    }
}

// ---------------------------------------------------------------------------
extern "C" void kernel_launch(void* const* d_in, const int* in_sizes, int n_in,
                              void* d_out, int out_size, void* d_ws, size_t ws_size,
                              hipStream_t stream)
{
    const float* c4  = (const float*)d_in[0];
    const float* c5  = (const float*)d_in[1];
    const float* w1a = (const float*)d_in[2];
    const float* s1a = (const float*)d_in[3];
    const float* b1a = (const float*)d_in[4];
    const float* w1b = (const float*)d_in[5];
    const float* s1b = (const float*)d_in[6];
    const float* b1b = (const float*)d_in[7];
    const float* wr  = (const float*)d_in[8];
    const float* sr  = (const float*)d_in[9];
    const float* br  = (const float*)d_in[10];
    const float* w2  = (const float*)d_in[11];
    const float* s2  = (const float*)d_in[12];
    const float* b2  = (const float*)d_in[13];
    const float* wp  = (const float*)d_in[14];
    const float* bp  = (const float*)d_in[15];

    float* ws   = (float*)d_ws;
    float* p5a  = ws;                                // 1024*1600
    float* X    = p5a + 1024*NPIX;                   // 1280*1600
    float* p5c  = X + 1280*NPIX;                     // 1024*1600
    float* pred = p5c + 1024*NPIX;                   // 125*1600
    float* scores = pred + 125*NPIX;                 // 160000
    unsigned* hist1 = (unsigned*)(scores + 160000);  // 4096
    unsigned* hist2 = hist1 + 4096;                  // 4096
    unsigned* hist3 = hist2 + 4096;                  // 256
    unsigned* meta  = hist3 + 256;                   // 16
    float*    gt_val = (float*)(meta + 16);          // 128
    unsigned* gt_idx = (unsigned*)(gt_val + 128);    // 128
    unsigned* eq_idx = gt_idx + 128;                 // 1024

    size_t off = (size_t)((char*)(eq_idx + 1024) - (char*)d_ws);
    off = (off + 255) & ~(size_t)255;
    const size_t W1AS = (size_t)3*9*128*1024*8;      // shorts
    const size_t W2S  = (size_t)3*9*160*1024*8;
    const size_t APL  = (size_t)3*160*1764*8;
    short* w1as = (short*)((char*)d_ws + off);
    short* w1bs = w1as + W1AS;
    short* w2s  = w1bs + W1AS;
    short* apl  = w2s  + W2S;
    float* part = (float*)(apl + APL);               // 5*1600*1024 floats
    const size_t WS_NEEDED = (size_t)((char*)(part + (size_t)5*1600*1024) - (char*)d_ws);
    const bool use_mfma = (ws_size >= WS_NEEDED);

    hipMemsetAsync(hist1, 0, (4096 + 4096 + 256 + 16) * sizeof(unsigned), stream);

    if (use_mfma) {
        hipMemsetAsync(apl, 0, APL * sizeof(short), stream);   // zero borders
        split_w_kernel<1024><<<512, 256, 0, stream>>>(w1a, w1as);
        split_w_kernel<1024><<<512, 256, 0, stream>>>(w1b, w1bs);
        split_w_kernel<1280><<<640, 256, 0, stream>>>(w2,  w2s);

        split_a_kernel<1024><<<800, 256, 0, stream>>>(c5, apl);
        conv3x3_mfma2<1024><<<dim3(25,16,4), 64, 0, stream>>>(apl, w1as, part);
        reduce_bn_kernel<<<dim3(25,16), 256, 0, stream>>>(part, 4, s1a, b1a, p5a);

        split_a_kernel<1024><<<800, 256, 0, stream>>>(p5a, apl);
        conv3x3_mfma2<1024><<<dim3(25,16,4), 64, 0, stream>>>(apl, w1bs, part);
        reduce_bn_kernel<<<dim3(25,16), 256, 0, stream>>>(part, 4, s1b, b1b, X + 256*NPIX);

        conv1x1_reorg_kernel<<<100, 256, 0, stream>>>(c4, wr, sr, br, X);
        split_a_kernel<1280><<<1000, 256, 0, stream>>>(X, apl);
        conv3x3_mfma2<1280><<<dim3(25,16,5), 64, 0, stream>>>(apl, w2s, part);
        reduce_bn_kernel<<<dim3(25,16), 256, 0, stream>>>(part, 5, s2, b2, p5c);
    } else {
        const dim3 g3(5, 5, 32);
        conv3x3_kernel<1024><<<g3, 256, 0, stream>>>(c5,  w1a, s1a, b1a, p5a);
        conv3x3_kernel<1024><<<g3, 256, 0, stream>>>(p5a, w1b, s1b, b1b, X + 256*NPIX);
        conv1x1_reorg_kernel<<<100, 256, 0, stream>>>(c4, wr, sr, br, X);
        conv3x3_kernel<1280><<<g3, 256, 0, stream>>>(X, w2, s2, b2, p5c);
    }

    conv1x1_pred_kernel<<<50, 256, 0, stream>>>(p5c, wp, pred);

    score_kernel<<<32, 256, 0, stream>>>(pred, bp, scores);
    hist1_kernel<<<80, 256, 0, stream>>>(scores, hist1);
    scan_kernel<<<1, 256, 0, stream>>>(hist1, 4096, meta, 1);
    hist2_kernel<<<625, 256, 0, stream>>>(scores, meta, hist2);
    scan_kernel<<<1, 256, 0, stream>>>(hist2, 4096, meta, 2);
    hist3_kernel<<<625, 256, 0, stream>>>(scores, meta, hist3);
    scan_kernel<<<1, 256, 0, stream>>>(hist3, 256, meta, 3);
    collect_kernel<<<625, 256, 0, stream>>>(scores, meta, gt_val, gt_idx, eq_idx);
    final_kernel<<<1, 128, 0, stream>>>(pred, bp, meta, gt_val, gt_idx, eq_idx, (float*)d_out);
}

// Round 6
// 1123.960 us; speedup vs baseline: 22.5801x; 1.4646x over previous
//
#include <hip/hip_runtime.h>
#include <math.h>

#define NPIX 1600   // 40*40

typedef short  s16x8  __attribute__((ext_vector_type(8)));
typedef float  f32x16 __attribute__((ext_vector_type(16)));

typedef const __attribute__((address_space(1))) void gas_t;
typedef __attribute__((address_space(3))) void las_t;
#define GLL16(g, l) __builtin_amdgcn_global_load_lds((gas_t*)(g), (las_t*)(l), 16, 0, 0)

__constant__ float c_aw[5] = {1.19f, 2.79f, 4.53f, 8.06f, 10.32f};
__constant__ float c_ah[5] = {1.98f, 4.59f, 8.92f, 5.29f, 10.65f};

__device__ __forceinline__ unsigned short bf16_rne(float x) {
    unsigned u = __float_as_uint(x);
    unsigned r = (u + 0x7FFFu + ((u >> 16) & 1u)) >> 16;
    return (unsigned short)r;
}
__device__ __forceinline__ float bf16_tof(unsigned short b) {
    return __uint_as_float((unsigned)b << 16);
}
__device__ __forceinline__ void split3(float x, short& o0, short& o1, short& o2) {
    const unsigned short b0 = bf16_rne(x);
    const float r1 = x - bf16_tof(b0);
    const unsigned short b1 = bf16_rne(r1);
    const float r2 = r1 - bf16_tof(b1);
    const unsigned short b2 = bf16_rne(r2);
    o0 = (short)b0; o1 = (short)b1; o2 = (short)b2;
}

// ---------------------------------------------------------------------------
// Weight pre-split: fp32 [1024][CIN][9] -> bf16x3 planes [term][tap][icg][oc][8ic]
// ---------------------------------------------------------------------------
template<int CIN>
__global__ __launch_bounds__(256)
void split_w_kernel(const float* __restrict__ w, short* __restrict__ wsp)
{
    const int g   = blockIdx.x * 256 + threadIdx.x;
    const int oc  = g & 1023;
    const int icg = g >> 10;
    if (icg >= CIN / 8) return;

    float v[72];
    const float* src = w + ((size_t)oc * CIN + icg * 8) * 9;
#pragma unroll
    for (int m = 0; m < 18; ++m) {
        const float4 q = ((const float4*)src)[m];
        v[m*4+0] = q.x; v[m*4+1] = q.y; v[m*4+2] = q.z; v[m*4+3] = q.w;
    }
    const size_t ICG = CIN / 8;
#pragma unroll
    for (int tap = 0; tap < 9; ++tap) {
        s16x8 t0, t1, t2;
#pragma unroll
        for (int ii = 0; ii < 8; ++ii) {
            short a0, a1, a2;
            split3(v[ii*9 + tap], a0, a1, a2);
            t0[ii] = a0; t1[ii] = a1; t2[ii] = a2;
        }
        const size_t base = (((size_t)tap * ICG + icg) * 1024 + oc) * 8;
        const size_t tstr = (size_t)9 * ICG * 1024 * 8;
        *(s16x8*)&wsp[base]          = t0;
        *(s16x8*)&wsp[base + tstr]   = t1;
        *(s16x8*)&wsp[base + 2*tstr] = t2;
    }
}

// ---------------------------------------------------------------------------
// Activation pre-split: fp32 [NCH][40][40] -> padded bf16x3 planes
// [term][ICGTOT][42][42][8ic] at icg offset ICGOFF. Borders pre-zeroed.
// ---------------------------------------------------------------------------
template<int NCH, int ICGTOT, int ICGOFF>
__global__ __launch_bounds__(256)
void split_a_kernel(const float* __restrict__ in, short* __restrict__ ap)
{
    constexpr int NICG = NCH / 8;
    const int id  = blockIdx.x * 256 + threadIdx.x;
    const int icg = id / 1600;
    const int px  = id - icg * 1600;
    if (icg >= NICG) return;
    const int py = px / 40, pxx = px - py*40;

    s16x8 o0, o1, o2;
#pragma unroll
    for (int ii = 0; ii < 8; ++ii) {
        short a0, a1, a2;
        split3(in[(size_t)(icg*8 + ii) * NPIX + px], a0, a1, a2);
        o0[ii] = a0; o1[ii] = a1; o2[ii] = a2;
    }
    const size_t dst  = ((size_t)(ICGOFF + icg) * 1764 + (py+1)*42 + (pxx+1)) * 8;
    const size_t tstr = (size_t)ICGTOT * 1764 * 8;
    *(s16x8*)&ap[dst]          = o0;
    *(s16x8*)&ap[dst + tstr]   = o1;
    *(s16x8*)&ap[dst + 2*tstr] = o2;
}

// ---------------------------------------------------------------------------
// MFMA conv3x3 v3: 128-thread (2-wave) blocks, tile 64px(8x8) x 64oc
// (each wave 64px x 32oc). Single compact LDS A-chunk (9.6 KB), barrier-synced.
// B direct from L2 with 3-slot tap prefetch. KS = ICG/32 K-split over z.
// Accumulation order per output identical to round-5 (bitwise-same results).
// ---------------------------------------------------------------------------
template<int ICG>   // ICG = CIN/8 (128 or 160)
__global__ __launch_bounds__(128, 3)
void conv3x3_mfma3(const short* __restrict__ ap, const short* __restrict__ wsp,
                   float* __restrict__ part)
{
    const int pxt = blockIdx.x;                 // 0..24
    const int xt = pxt % 5, yt = pxt / 5;
    const int tid  = threadIdx.x;
    const int lane = tid & 63;
    const int wv   = tid >> 6;
    const int ocb  = (blockIdx.y << 6) + (wv << 5);   // this wave's 32 oc
    const int ks   = blockIdx.z;

    __shared__ __align__(16) short Abuf[4800];  // [(t*2+h)*100 + ppx][8ic] compact

    const int rr = lane & 31;
    const int h  = lane >> 5;

    const int pb0 = (rr >> 3)*10 + (rr & 7);    // px of this lane, m-subtile 0
    const int pb1 = pb0 + 40;                   // +4 rows (10-wide patch)
    const short* pB = wsp + (size_t)h*8192 + (size_t)(ocb + rr)*8;

    f32x16 acc[2];
#pragma unroll
    for (int m2 = 0; m2 < 2; ++m2)
#pragma unroll
        for (int i = 0; i < 16; ++i) acc[m2][i] = 0.f;

    const int icgS = ks * 32;

    for (int c = 0; c < 16; ++c) {
        const int icg0 = icgS + 2*c;
        __syncthreads();                       // all waves done reading Abuf
        // STAGE: 600 x 16B units, both waves
#pragma unroll
        for (int r = 0; r < 5; ++r) {
            const int u = r*128 + tid;
            if (u < 600) {
                const int p   = u / 100;       // plane: t*2 + hh
                const int ppx = u - p*100;
                const int t   = p >> 1, hh = p & 1;
                const int pr  = ppx / 10, pc = ppx - pr*10;
                const short* g = ap + ((size_t)(t*ICG + icg0 + hh) * 1764
                                       + (yt*8 + pr)*42 + (xt*8 + pc)) * 8;
                short* l = &Abuf[(r*128 + wv*64) * 8];
                GLL16(g, l);
            }
        }
        // B preload taps 0,1 (VGPR, no LDS) — drains with the same vmcnt
        s16x8 bb[3][3];
#pragma unroll
        for (int tt = 0; tt < 2; ++tt)
#pragma unroll
            for (int t = 0; t < 3; ++t)
                bb[tt][t] = *(const s16x8*)(pB + ((size_t)(t*9 + tt)*ICG + icg0)*8192);
        asm volatile("s_waitcnt vmcnt(0)" ::: "memory");
        __syncthreads();

        const short* AB = &Abuf[h*800];
#pragma unroll
        for (int tap = 0; tap < 9; ++tap) {
            const int dy = tap/3, dx = tap - dy*3;
            s16x8 a[3][2];
#pragma unroll
            for (int t = 0; t < 3; ++t) {
                a[t][0] = *(const s16x8*)(AB + (size_t)t*1600 + (size_t)(pb0 + dy*10 + dx)*8);
                a[t][1] = *(const s16x8*)(AB + (size_t)t*1600 + (size_t)(pb1 + dy*10 + dx)*8);
            }
            if (tap < 7) {
#pragma unroll
                for (int t = 0; t < 3; ++t)
                    bb[(tap+2)%3][t] =
                        *(const s16x8*)(pB + ((size_t)(t*9 + tap+2)*ICG + icg0)*8192);
            }
            constexpr int PA6[6] = {0,0,1,1,2,0};
            constexpr int PB6[6] = {0,1,0,1,0,2};
#pragma unroll
            for (int p = 0; p < 6; ++p)
#pragma unroll
                for (int m2 = 0; m2 < 2; ++m2)
                    acc[m2] = __builtin_amdgcn_mfma_f32_32x32x16_bf16(
                        a[PA6[p]][m2], bb[tap%3][PB6[p]], acc[m2], 0, 0, 0);
        }
    }

    // epilogue: coalesced partial stores, layout part[ks][px][oc]
    float* pbase = part + (size_t)ks * (1600*1024);
#pragma unroll
    for (int m2 = 0; m2 < 2; ++m2)
#pragma unroll
        for (int i = 0; i < 16; ++i) {
            const int row = (i & 3) + 8*(i >> 2) + 4*h;
            const int pxl = m2*32 + row;
            const int pxg = (yt*8 + (pxl >> 3))*40 + xt*8 + (pxl & 7);
            pbase[(size_t)pxg*1024 + ocb + rr] = acc[m2][i];
        }
}

// ---------------------------------------------------------------------------
// reduce partials (fixed order) + BN + lrelu -> bf16x3 split planes (fused)
// ---------------------------------------------------------------------------
template<int ICGTOT>
__global__ __launch_bounds__(256)
void reduce_bn_split_kernel(const float* __restrict__ part, const int KS,
                            const float* __restrict__ scale, const float* __restrict__ shift,
                            short* __restrict__ ap, const int icgoff)
{
    const int pxt = blockIdx.x;
    const int xt = pxt % 5, yt = pxt / 5;
    const int ocb = blockIdx.y << 6;
    const int t = threadIdx.x;
    __shared__ float eb[64*65];   // [ocl][pxl], stride 65 (bank-safe)

    float s[16];
#pragma unroll
    for (int j = 0; j < 16; ++j) s[j] = 0.f;
    for (int ks = 0; ks < KS; ++ks) {
        const float* pb = part + (size_t)ks * (1600*1024);
#pragma unroll
        for (int j = 0; j < 16; ++j) {
            const int e = t + j*256;
            const int pxl = e >> 6, ocl = e & 63;
            const int pxg = (yt*8 + (pxl >> 3))*40 + xt*8 + (pxl & 7);
            s[j] += pb[(size_t)pxg*1024 + ocb + ocl];
        }
    }
#pragma unroll
    for (int j = 0; j < 16; ++j) {
        const int e = t + j*256;
        const int pxl = e >> 6, ocl = e & 63;
        float v = fmaf(s[j], scale[ocb+ocl], shift[ocb+ocl]);
        eb[ocl*65 + pxl] = v > 0.f ? v : 0.1f*v;
    }
    __syncthreads();

    const size_t tstr = (size_t)ICGTOT * 1764 * 8;
#pragma unroll
    for (int q = 0; q < 2; ++q) {
        const int u = t + q*256;            // 512 units: [icg_l 8][pxl 64]
        const int icg_l = u >> 6, pxl = u & 63;
        s16x8 o0, o1, o2;
#pragma unroll
        for (int ii = 0; ii < 8; ++ii) {
            short a0, a1, a2;
            split3(eb[(icg_l*8 + ii)*65 + pxl], a0, a1, a2);
            o0[ii] = a0; o1[ii] = a1; o2[ii] = a2;
        }
        const int py  = yt*8 + (pxl >> 3);
        const int pxx = xt*8 + (pxl & 7);
        const size_t dst = ((size_t)(icgoff + (ocb >> 3) + icg_l) * 1764
                            + (py+1)*42 + (pxx+1)) * 8;
        *(s16x8*)&ap[dst]          = o0;
        *(s16x8*)&ap[dst + tstr]   = o1;
        *(s16x8*)&ap[dst + 2*tstr] = o2;
    }
}

// ---------------------------------------------------------------------------
// reduce partials + BN + lrelu -> fp32 [oc][px] (for the final conv output)
// ---------------------------------------------------------------------------
__global__ __launch_bounds__(256)
void reduce_bn_kernel(const float* __restrict__ part, const int KS,
                      const float* __restrict__ scale, const float* __restrict__ shift,
                      float* __restrict__ out)
{
    const int pxt = blockIdx.x;
    const int xt = pxt % 5, yt = pxt / 5;
    const int ocb = blockIdx.y << 6;
    const int t = threadIdx.x;
    __shared__ float eb[64*72];

    float s[16];
#pragma unroll
    for (int j = 0; j < 16; ++j) s[j] = 0.f;
    for (int ks = 0; ks < KS; ++ks) {
        const float* pb = part + (size_t)ks * (1600*1024);
#pragma unroll
        for (int j = 0; j < 16; ++j) {
            const int e = t + j*256;
            const int pxl = e >> 6, ocl = e & 63;
            const int pxg = (yt*8 + (pxl >> 3))*40 + xt*8 + (pxl & 7);
            s[j] += pb[(size_t)pxg*1024 + ocb + ocl];
        }
    }
#pragma unroll
    for (int j = 0; j < 16; ++j) {
        const int e = t + j*256;
        const int pxl = e >> 6, ocl = e & 63;
        float v = fmaf(s[j], scale[ocb+ocl], shift[ocb+ocl]);
        eb[ocl*72 + pxl] = v > 0.f ? v : 0.1f*v;
    }
    __syncthreads();
    const int ocl = t >> 2, seg = t & 3;
#pragma unroll
    for (int q = 0; q < 2; ++q) {
        const int rw = seg*2 + q;
        float4 v0 = *(float4*)&eb[ocl*72 + rw*8];
        float4 v1 = *(float4*)&eb[ocl*72 + rw*8 + 4];
        float* op = out + (size_t)(ocb + ocl)*NPIX + (yt*8 + rw)*40 + xt*8;
        *(float4*)op = v0;
        *(float4*)(op + 4) = v1;
    }
}

// ---------------------------------------------------------------------------
// FALLBACK fp32 conv3x3 (round-3 structure) used if ws too small
// ---------------------------------------------------------------------------
template<int CIN>
__global__ __launch_bounds__(256)
void conv3x3_kernel(const float* __restrict__ in, const float* __restrict__ w,
                    const float* __restrict__ scale, const float* __restrict__ shift,
                    float* __restrict__ out)
{
    const int ox  = blockIdx.x, oy = blockIdx.y;
    const int ocb = blockIdx.z << 5;
    const int tid = threadIdx.x;
    const int tx  = tid & 15;
    const int ty  = tid >> 4;
    const int r    = ty >> 1;
    const int xoff = (ty & 1) << 2;

    __shared__ float wl[8*9*32];
    __shared__ float patch[8*10*12];

    float acc[4][2];
#pragma unroll
    for (int j = 0; j < 4; ++j) { acc[j][0] = 0.f; acc[j][1] = 0.f; }

    const int y0 = oy*8 - 1;
    const int x0 = ox*8 - 1;

    for (int c0 = 0; c0 < CIN; c0 += 8) {
        __syncthreads();
        if (tid < 64) {
            const int o  = tid >> 1;
            const int rh = (tid & 1) * 36;
            const float* wp = w + (size_t)(ocb + o)*(CIN*9) + c0*9 + rh;
#pragma unroll
            for (int m = 0; m < 9; ++m) {
                const float4 v = ((const float4*)wp)[m];
                const int rw = rh + m*4;
                wl[(rw+0)*32 + o] = v.x;
                wl[(rw+1)*32 + o] = v.y;
                wl[(rw+2)*32 + o] = v.z;
                wl[(rw+3)*32 + o] = v.w;
            }
        } else {
            const int t = tid - 64;
            for (int e = t; e < 800; e += 192) {
                const int ch  = e / 100;
                const int rem = e - ch*100;
                const int py  = rem / 10;
                const int pxx = rem - py*10;
                const int gy = y0 + py, gx = x0 + pxx;
                float v = 0.f;
                if ((unsigned)gy < 40u && (unsigned)gx < 40u)
                    v = in[(size_t)(c0+ch)*NPIX + gy*40 + gx];
                patch[ch*120 + py*12 + pxx] = v;
            }
        }
        __syncthreads();
#pragma unroll
        for (int i = 0; i < 8; ++i) {
#pragma unroll
            for (int dy = 0; dy < 3; ++dy) {
                const float* prow = &patch[i*120 + (r+dy)*12 + xoff];
                float a[6];
#pragma unroll
                for (int q = 0; q < 6; ++q) a[q] = prow[q];
#pragma unroll
                for (int dx = 0; dx < 3; ++dx) {
                    const float2 b = *(const float2*)&wl[(i*9 + dy*3 + dx)*32 + (tx<<1)];
#pragma unroll
                    for (int j = 0; j < 4; ++j) {
                        const float av = a[dx + j];
                        acc[j][0] = fmaf(av, b.x, acc[j][0]);
                        acc[j][1] = fmaf(av, b.y, acc[j][1]);
                    }
                }
            }
        }
    }

    const int gy = oy*8 + r;
    const int gx = ox*8 + xoff;
#pragma unroll
    for (int k = 0; k < 2; ++k) {
        const int oc = ocb + (tx<<1) + k;
        const float s = scale[oc], sh = shift[oc];
        float4 o4; float v;
        v = fmaf(acc[0][k], s, sh); o4.x = v > 0.f ? v : 0.1f*v;
        v = fmaf(acc[1][k], s, sh); o4.y = v > 0.f ? v : 0.1f*v;
        v = fmaf(acc[2][k], s, sh); o4.z = v > 0.f ? v : 0.1f*v;
        v = fmaf(acc[3][k], s, sh); o4.w = v > 0.f ? v : 0.1f*v;
        *(float4*)&out[(size_t)oc*NPIX + gy*40 + gx] = o4;
    }
}

// ---------------------------------------------------------------------------
// conv1x1 512->64 @80x80 + BN + lrelu + reorg(s=2), writes X channels 0..255
// ---------------------------------------------------------------------------
__global__ __launch_bounds__(256)
void conv1x1_reorg_kernel(const float* __restrict__ in, const float* __restrict__ w,
                          const float* __restrict__ scale, const float* __restrict__ shift,
                          float* __restrict__ X)
{
    const int px0 = blockIdx.x << 6;
    const int tid = threadIdx.x;
    const int tx  = tid & 15;
    const int ty  = tid >> 4;

    __shared__ float il[8*64];
    __shared__ float wlr[8*64];

    float acc[4][4];
#pragma unroll
    for (int j = 0; j < 4; ++j)
#pragma unroll
        for (int k = 0; k < 4; ++k) acc[j][k] = 0.f;

    for (int c0 = 0; c0 < 512; c0 += 8) {
        __syncthreads();
        {
            int e = tid;
#pragma unroll
            for (int q = 0; q < 2; ++q, e += 256) {
                const int ch = e >> 6, p = e & 63;
                il[ch*64 + p] = in[(size_t)(c0+ch)*6400 + px0 + p];
            }
            e = tid;
#pragma unroll
            for (int q = 0; q < 2; ++q, e += 256) {
                const int o = e >> 3, cc = e & 7;
                wlr[cc*64 + o] = w[o*512 + c0 + cc];
            }
        }
        __syncthreads();
#pragma unroll
        for (int cc = 0; cc < 8; ++cc) {
            const float4 a4 = *(const float4*)&il[cc*64 + (ty<<2)];
            const float4 b4 = *(const float4*)&wlr[cc*64 + (tx<<2)];
            const float a[4] = {a4.x, a4.y, a4.z, a4.w};
            const float b[4] = {b4.x, b4.y, b4.z, b4.w};
#pragma unroll
            for (int j = 0; j < 4; ++j)
#pragma unroll
                for (int k = 0; k < 4; ++k)
                    acc[j][k] = fmaf(a[j], b[k], acc[j][k]);
        }
    }

#pragma unroll
    for (int j = 0; j < 4; ++j) {
        const int px = px0 + (ty<<2) + j;
        const int y2 = px / 80, x2 = px - y2*80;
        const int q  = (y2 & 1)*2 + (x2 & 1);
        const int yo = y2 >> 1, xo = x2 >> 1;
#pragma unroll
        for (int k = 0; k < 4; ++k) {
            const int oc = (tx<<2) + k;
            float v = fmaf(acc[j][k], scale[oc], shift[oc]);
            v = v > 0.f ? v : 0.1f*v;
            X[(size_t)(q*64 + oc)*NPIX + yo*40 + xo] = v;
        }
    }
}

// ---------------------------------------------------------------------------
// conv1x1 1024->125 @40x40 (no bias; readers add bp)
// ---------------------------------------------------------------------------
__global__ __launch_bounds__(256)
void conv1x1_pred_kernel(const float* __restrict__ in, const float* __restrict__ w,
                         float* __restrict__ pred)
{
    const int px0 = blockIdx.x << 5;
    const int tid = threadIdx.x;
    const int tx  = tid & 15;
    const int ty  = tid >> 4;

    __shared__ float il[8*32];
    __shared__ float wlp[8*128];

    float acc[2][8];
#pragma unroll
    for (int j = 0; j < 2; ++j)
#pragma unroll
        for (int k = 0; k < 8; ++k) acc[j][k] = 0.f;

    for (int c0 = 0; c0 < 1024; c0 += 8) {
        __syncthreads();
        {
            const int ch = tid >> 5, p = tid & 31;
            il[ch*32 + p] = in[(size_t)(c0+ch)*NPIX + px0 + p];
        }
#pragma unroll
        for (int q = 0; q < 4; ++q) {
            const int e = tid + q*256;
            const int o = e >> 3, cc = e & 7;
            wlp[cc*128 + o] = (o < 125) ? w[o*1024 + c0 + cc] : 0.f;
        }
        __syncthreads();
#pragma unroll
        for (int cc = 0; cc < 8; ++cc) {
            const float a0 = il[cc*32 + (ty<<1)];
            const float a1 = il[cc*32 + (ty<<1) + 1];
            const float4 b0 = *(const float4*)&wlp[cc*128 + (tx<<3)];
            const float4 b1 = *(const float4*)&wlp[cc*128 + (tx<<3) + 4];
            const float b[8] = {b0.x,b0.y,b0.z,b0.w,b1.x,b1.y,b1.z,b1.w};
#pragma unroll
            for (int k = 0; k < 8; ++k) {
                acc[0][k] = fmaf(a0, b[k], acc[0][k]);
                acc[1][k] = fmaf(a1, b[k], acc[1][k]);
            }
        }
    }
#pragma unroll
    for (int k = 0; k < 8; ++k) {
        const int oc = (tx<<3) + k;
        if (oc < 125) {
#pragma unroll
            for (int j = 0; j < 2; ++j)
                pred[(size_t)oc*NPIX + px0 + (ty<<1) + j] = acc[j][k];
        }
    }
}

// ---------------------------------------------------------------------------
// scores = sigmoid(conf) * softmax(cls) for 8000 (px,anchor) pairs
// ---------------------------------------------------------------------------
__global__ __launch_bounds__(256)
void score_kernel(const float* __restrict__ pred, const float* __restrict__ bp,
                  float* __restrict__ scores)
{
    const int id = blockIdx.x*256 + threadIdx.x;
    if (id >= 8000) return;
    const int a  = id / 1600;
    const int px = id - a*1600;
    const float conf = pred[a*NPIX + px] + bp[a];
    float cls[20];
    float m = -INFINITY;
#pragma unroll
    for (int c = 0; c < 20; ++c) {
        cls[c] = pred[(5 + a*20 + c)*NPIX + px] + bp[5 + a*20 + c];
        m = fmaxf(m, cls[c]);
    }
    float ssum = 0.f;
#pragma unroll
    for (int c = 0; c < 20; ++c) { cls[c] = expf(cls[c] - m); ssum += cls[c]; }
    const float sig = 1.f / (1.f + expf(-conf));
    const float f = sig / ssum;
    const int base = (px*5 + a)*20;
#pragma unroll
    for (int c = 0; c < 20; ++c) scores[base + c] = cls[c] * f;
}

// ---------------------------------------------------------------------------
// exact top-100 via 3-level radix select on positive-float bits (12/12/8)
// ---------------------------------------------------------------------------
__global__ __launch_bounds__(256)
void hist1_kernel(const float* __restrict__ scores, unsigned* __restrict__ hist)
{
    __shared__ unsigned hh[4096];
    for (int i = threadIdx.x; i < 4096; i += 256) hh[i] = 0u;
    __syncthreads();
    for (int id = blockIdx.x*256 + threadIdx.x; id < 160000; id += 80*256)
        atomicAdd(&hh[__float_as_uint(scores[id]) >> 20], 1u);
    __syncthreads();
    for (int i = threadIdx.x; i < 4096; i += 256)
        if (hh[i]) atomicAdd(&hist[i], hh[i]);
}

__global__ __launch_bounds__(256)
void hist2_kernel(const float* __restrict__ scores, const unsigned* __restrict__ meta,
                  unsigned* __restrict__ hist)
{
    const int id = blockIdx.x*256 + threadIdx.x;
    if (id >= 160000) return;
    const unsigned u = __float_as_uint(scores[id]);
    if ((u >> 20) == meta[0]) atomicAdd(&hist[(u >> 8) & 0xFFFu], 1u);
}

__global__ __launch_bounds__(256)
void hist3_kernel(const float* __restrict__ scores, const unsigned* __restrict__ meta,
                  unsigned* __restrict__ hist)
{
    const int id = blockIdx.x*256 + threadIdx.x;
    if (id >= 160000) return;
    const unsigned u = __float_as_uint(scores[id]);
    const unsigned key = (meta[0] << 12) | meta[2];
    if ((u >> 8) == key) atomicAdd(&hist[u & 0xFFu], 1u);
}

__global__ __launch_bounds__(256)
void scan_kernel(const unsigned* __restrict__ hist, int nbins,
                 unsigned* __restrict__ meta, int mode)
{
    __shared__ unsigned seg[256];
    const int tid = threadIdx.x;
    const int spb = nbins >> 8;
    unsigned s = 0;
    for (int k = 0; k < spb; ++k) s += hist[tid*spb + k];
    seg[tid] = s;
    __syncthreads();
    if (tid == 0) {
        unsigned need = 100u;
        if (mode == 2) need = 100u - meta[1];
        else if (mode == 3) need = 100u - meta[3];
        unsigned cum = 0;
        int sgi = 255;
        while (sgi > 0 && cum + seg[sgi] < need) { cum += seg[sgi]; --sgi; }
        int b = sgi*spb + spb - 1;
        while (b > sgi*spb && cum + hist[b] < need) { cum += hist[b]; --b; }
        if (mode == 1)      { meta[0] = (unsigned)b; meta[1] = cum; }
        else if (mode == 2) { meta[2] = (unsigned)b; meta[3] = meta[1] + cum; }
        else {
            meta[4] = (meta[0] << 20) | (meta[2] << 8) | (unsigned)b;
            meta[5] = meta[3] + cum;
        }
    }
}

__global__ __launch_bounds__(256)
void collect_kernel(const float* __restrict__ scores, unsigned* __restrict__ meta,
                    float* __restrict__ gt_val, unsigned* __restrict__ gt_idx,
                    unsigned* __restrict__ eq_idx)
{
    const int id = blockIdx.x*256 + threadIdx.x;
    if (id >= 160000) return;
    const float v = scores[id];
    const unsigned u = __float_as_uint(v);
    const unsigned T = meta[4];
    if (u > T) {
        const unsigned p = atomicAdd(&meta[8], 1u);
        if (p < 128u) { gt_val[p] = v; gt_idx[p] = (unsigned)id; }
    } else if (u == T) {
        const unsigned p = atomicAdd(&meta[9], 1u);
        if (p < 1024u) eq_idx[p] = (unsigned)id;
    }
}

// ---------------------------------------------------------------------------
// final: assemble top-100 (stable ties), bitonic sort desc, decode, NMS, write
// ---------------------------------------------------------------------------
__global__ __launch_bounds__(128)
void final_kernel(const float* __restrict__ pred, const float* __restrict__ bp,
                  const unsigned* __restrict__ meta,
                  const float* __restrict__ gt_val, const unsigned* __restrict__ gt_idx,
                  const unsigned* __restrict__ eq_idx,
                  float* __restrict__ out)
{
    __shared__ float    sval[128];
    __shared__ unsigned sidx[128];
    __shared__ float bx1[100], by1[100], bx2[100], by2[100], sarea[100], sscore[100];
    __shared__ int   slab[100];
    __shared__ int   skeep[100];

    const int tid = threadIdx.x;
    const unsigned T    = meta[4];
    const unsigned n_gt = meta[5];
    const unsigned n_eq = meta[9] < 1024u ? meta[9] : 1024u;
    const int n_take = 100 - (int)n_gt;

    sval[tid] = -1.f;
    sidx[tid] = 0xFFFFFFFFu;
    if (tid < (int)n_gt) { sval[tid] = gt_val[tid]; sidx[tid] = gt_idx[tid]; }
    __syncthreads();
    if (tid == 0) {
        unsigned lastp1 = 0;
        const float tv = __uint_as_float(T);
        for (int t = 0; t < n_take; ++t) {
            unsigned best = 0xFFFFFFFFu;
            for (unsigned e = 0; e < n_eq; ++e) {
                const unsigned v = eq_idx[e];
                if (v >= lastp1 && v < best) best = v;
            }
            sval[n_gt + t] = tv;
            sidx[n_gt + t] = best;
            lastp1 = best + 1;
        }
    }
    __syncthreads();

    for (int k = 2; k <= 128; k <<= 1) {
        for (int j = k >> 1; j > 0; j >>= 1) {
            const int ixj = tid ^ j;
            if (ixj > tid) {
                const float v0 = sval[tid], v1 = sval[ixj];
                const unsigned i0 = sidx[tid], i1 = sidx[ixj];
                const bool prec = (v0 > v1) || (v0 == v1 && i0 < i1);
                const bool asc  = ((tid & k) == 0);
                if (asc ? !prec : prec) {
                    sval[tid] = v1; sval[ixj] = v0;
                    sidx[tid] = i1; sidx[ixj] = i0;
                }
            }
            __syncthreads();
        }
    }

    if (tid < 100) {
        const float sc = sval[tid];
        const unsigned idx = sidx[tid];
        const int ai   = (int)(idx / 20u);
        const int lab  = (int)(idx - (unsigned)ai*20u);
        const int cell = ai / 5;
        const int a    = ai - cell*5;
        const int gx = cell % 40, gy = cell / 40;
        const int rb = 105 + a*4;
        const float t0 = pred[(rb+0)*NPIX + cell] + bp[rb+0];
        const float t1 = pred[(rb+1)*NPIX + cell] + bp[rb+1];
        const float t2 = pred[(rb+2)*NPIX + cell] + bp[rb+2];
        const float t3 = pred[(rb+3)*NPIX + cell] + bp[rb+3];
        const float cx = (1.f/(1.f+expf(-t0)) + (float)gx) * 32.f;
        const float cy = (1.f/(1.f+expf(-t1)) + (float)gy) * 32.f;
        const float bw = expf(t2) * c_aw[a] * 32.f;
        const float bh = expf(t3) * c_ah[a] * 32.f;
        bx1[tid] = cx - 0.5f*bw;
        by1[tid] = cy - 0.5f*bh;
        bx2[tid] = cx + 0.5f*bw;
        by2[tid] = cy + 0.5f*bh;
        sarea[tid]  = (bx2[tid]-bx1[tid]) * (by2[tid]-by1[tid]);
        slab[tid]   = lab;
        sscore[tid] = sc;
        skeep[tid]  = (sc > 0.001f) ? 1 : 0;
    }
    __syncthreads();

    for (int i = 0; i < 99; ++i) {
        if (tid < 100 && tid > i) {
            if (skeep[i] && skeep[tid] && slab[tid] == slab[i]) {
                const float xx1 = fmaxf(bx1[i], bx1[tid]);
                const float yy1 = fmaxf(by1[i], by1[tid]);
                const float xx2 = fminf(bx2[i], bx2[tid]);
                const float yy2 = fminf(by2[i], by2[tid]);
                const float inter = fmaxf(1e-10f, xx2-xx1) * fmaxf(1e-10f, yy2-yy1);
                const float iou = inter / (sarea[i] + sarea[tid] - inter);
                if (iou > 0.6f) skeep[tid] = 0;
            }
        }
        __syncthreads();
    }

    if (tid < 100) {
        const bool kp = skeep[tid] != 0;
        const float q[4] = {bx1[tid], by1[tid], bx2[tid], by2[tid]};
#pragma unroll
        for (int k = 0; k < 4; ++k) {
            float v = q[k] / 1280.f;
            v = fminf(fmaxf(v, 0.f), 1.f);
            out[tid*4 + k] = kp ? v : 0.f;
        }
        out[400 + tid] = kp ? sscore[tid] : 0.f;
        out[500 + tid] = kp ? (float)slab[tid] : -1.f;
        out[600 + tid] = kp ? 1.f : 0.f;
    }
}

// ---------------------------------------------------------------------------
extern "C" void kernel_launch(void* const* d_in, const int* in_sizes, int n_in,
                              void* d_out, int out_size, void* d_ws, size_t ws_size,
                              hipStream_t stream)
{
    const float* c4  = (const float*)d_in[0];
    const float* c5  = (const float*)d_in[1];
    const float* w1a = (const float*)d_in[2];
    const float* s1a = (const float*)d_in[3];
    const float* b1a = (const float*)d_in[4];
    const float* w1b = (const float*)d_in[5];
    const float* s1b = (const float*)d_in[6];
    const float* b1b = (const float*)d_in[7];
    const float* wr  = (const float*)d_in[8];
    const float* sr  = (const float*)d_in[9];
    const float* br  = (const float*)d_in[10];
    const float* w2  = (const float*)d_in[11];
    const float* s2  = (const float*)d_in[12];
    const float* b2  = (const float*)d_in[13];
    const float* wp  = (const float*)d_in[14];
    const float* bp  = (const float*)d_in[15];

    float* ws   = (float*)d_ws;
    float* p5a  = ws;                                // 1024*1600 (fallback only)
    float* X    = p5a + 1024*NPIX;                   // 1280*1600 (mfma: first 256 ch)
    float* p5c  = X + 1280*NPIX;                     // 1024*1600
    float* pred = p5c + 1024*NPIX;                   // 125*1600
    float* scores = pred + 125*NPIX;                 // 160000
    unsigned* hist1 = (unsigned*)(scores + 160000);  // 4096
    unsigned* hist2 = hist1 + 4096;                  // 4096
    unsigned* hist3 = hist2 + 4096;                  // 256
    unsigned* meta  = hist3 + 256;                   // 16
    float*    gt_val = (float*)(meta + 16);          // 128
    unsigned* gt_idx = (unsigned*)(gt_val + 128);    // 128
    unsigned* eq_idx = gt_idx + 128;                 // 1024

    size_t off = (size_t)((char*)(eq_idx + 1024) - (char*)d_ws);
    off = (off + 255) & ~(size_t)255;
    const size_t WBUF = (size_t)3*9*160*1024*8;      // shorts (max, CIN=1280)
    const size_t APLA = (size_t)3*128*1764*8;        // shorts
    const size_t APLB = (size_t)3*160*1764*8;        // shorts
    short* wbuf = (short*)((char*)d_ws + off);
    short* aplA = wbuf + WBUF;
    short* aplB = aplA + APLA;
    float* part = (float*)(aplB + APLB);             // 5*1600*1024 floats
    const size_t WS_NEEDED = (size_t)((char*)(part + (size_t)5*1600*1024) - (char*)d_ws);
    const bool use_mfma = (ws_size >= WS_NEEDED);

    hipMemsetAsync(hist1, 0, (4096 + 4096 + 256 + 16) * sizeof(unsigned), stream);

    if (use_mfma) {
        hipMemsetAsync(aplA, 0, (APLA + APLB) * sizeof(short), stream);  // zero borders

        // conv1: c5 -> (w1a) -> split planes (aplA)
        split_a_kernel<1024,128,0><<<800, 256, 0, stream>>>(c5, aplA);
        split_w_kernel<1024><<<512, 256, 0, stream>>>(w1a, wbuf);
        conv3x3_mfma3<128><<<dim3(25,16,4), 128, 0, stream>>>(aplA, wbuf, part);
        reduce_bn_split_kernel<128><<<dim3(25,16), 256, 0, stream>>>(part, 4, s1a, b1a, aplA, 0);

        // conv2: (aplA) -> (w1b) -> split planes (aplB, icg 32..159)
        split_w_kernel<1024><<<512, 256, 0, stream>>>(w1b, wbuf);
        conv3x3_mfma3<128><<<dim3(25,16,4), 128, 0, stream>>>(aplA, wbuf, part);
        reduce_bn_split_kernel<160><<<dim3(25,16), 256, 0, stream>>>(part, 4, s1b, b1b, aplB, 32);

        // reorg: c4 -> X (256 ch fp32) -> split planes (aplB, icg 0..31)
        conv1x1_reorg_kernel<<<100, 256, 0, stream>>>(c4, wr, sr, br, X);
        split_a_kernel<256,160,0><<<200, 256, 0, stream>>>(X, aplB);

        // conv3: (aplB) -> (w2) -> fp32 p5c
        split_w_kernel<1280><<<640, 256, 0, stream>>>(w2, wbuf);
        conv3x3_mfma3<160><<<dim3(25,16,5), 128, 0, stream>>>(aplB, wbuf, part);
        reduce_bn_kernel<<<dim3(25,16), 256, 0, stream>>>(part, 5, s2, b2, p5c);
    } else {
        const dim3 g3(5, 5, 32);
        conv3x3_kernel<1024><<<g3, 256, 0, stream>>>(c5,  w1a, s1a, b1a, p5a);
        conv3x3_kernel<1024><<<g3, 256, 0, stream>>>(p5a, w1b, s1b, b1b, X + 256*NPIX);
        conv1x1_reorg_kernel<<<100, 256, 0, stream>>>(c4, wr, sr, br, X);
        conv3x3_kernel<1280><<<g3, 256, 0, stream>>>(X, w2, s2, b2, p5c);
    }

    conv1x1_pred_kernel<<<50, 256, 0, stream>>>(p5c, wp, pred);

    score_kernel<<<32, 256, 0, stream>>>(pred, bp, scores);
    hist1_kernel<<<80, 256, 0, stream>>>(scores, hist1);
    scan_kernel<<<1, 256, 0, stream>>>(hist1, 4096, meta, 1);
    hist2_kernel<<<625, 256, 0, stream>>>(scores, meta, hist2);
    scan_kernel<<<1, 256, 0, stream>>>(hist2, 4096, meta, 2);
    hist3_kernel<<<625, 256, 0, stream>>>(scores, meta, hist3);
    scan_kernel<<<1, 256, 0, stream>>>(hist3, 256, meta, 3);
    collect_kernel<<<625, 256, 0, stream>>>(scores, meta, gt_val, gt_idx, eq_idx);
    final_kernel<<<1, 128, 0, stream>>>(pred, bp, meta, gt_val, gt_idx, eq_idx, (float*)d_out);
}